// Round 4
// baseline (273.534 us; speedup 1.0000x reference)
//
#include <hip/hip_runtime.h>
#include <cstdint>
#include <cstddef>

#define LQ   2048
#define BQ   4
#define EQ   1024
#define HQ   8
#define D1Q  2048
#define HDQ  256
#define NBQ  (LQ*BQ)   // 8192 rows in (n,b) layout

typedef __bf16 bf16_t;
typedef __bf16 bf16x8 __attribute__((ext_vector_type(8)));
typedef __bf16 bf16x4 __attribute__((ext_vector_type(4)));
typedef float  f32x4  __attribute__((ext_vector_type(4)));

#define GAS1(p) ((const __attribute__((address_space(1))) void*)(p))
#define LAS3(p) ((__attribute__((address_space(3))) void*)(p))

// ---------------------------------------------------------------- utilities

__global__ __launch_bounds__(256) void convert_kernel(
    const float* __restrict__ Wu, const float* __restrict__ Wv,
    const float* __restrict__ Wo,
    bf16_t* __restrict__ Wub, bf16_t* __restrict__ Wvb,
    bf16_t* __restrict__ Wob)
{
    const size_t i = (size_t)blockIdx.x * 256 + threadIdx.x;
    if (i < (size_t)D1Q * EQ) {
        Wub[i] = (bf16_t)Wu[i];
        Wvb[i] = (bf16_t)Wv[i];
        Wob[i] = (bf16_t)Wo[i];
    }
}

// Precompute all Toeplitz A-tiles (128x32, diagonal offset (q-3)*32).
__global__ __launch_bounds__(256) void build_toep_tiles(
    const float* __restrict__ zero, const float* __restrict__ pos,
    bf16_t* __restrict__ Atiles)
{
    const int q = blockIdx.x;        // 0..63
    const int h = blockIdx.y;        // 0..7
    const int doff = (q - 3) * 32;
    const int tid = threadIdx.x;
    bf16_t* dst = Atiles + ((size_t)h * 64 + q) * (128 * 32);
    const int e0 = tid * 16;
    const int r = e0 >> 5;
    const int cbase = e0 & 31;
    bf16_t vals[16];
    #pragma unroll
    for (int j = 0; j < 16; ++j) {
        const int d = doff + r - (cbase + j);
        float v = 0.f;
        if (d == 0) v = zero[h];
        else if (d > 0) v = pos[(size_t)h * (LQ - 1) + d - 1];
        vals[j] = (bf16_t)v;
    }
    *(bf16x8*)(dst + e0)     = *(bf16x8*)(vals);
    *(bf16x8*)(dst + e0 + 8) = *(bf16x8*)(vals + 8);
}

__global__ __launch_bounds__(256) void rmsnorm_kernel(
    const float* __restrict__ x, bf16_t* __restrict__ xn)
{
    const int row = blockIdx.x;           // 0..8191
    const int tid = threadIdx.x;
    const float4 v = ((const float4*)(x + (size_t)row * EQ))[tid];
    float ss = v.x*v.x + v.y*v.y + v.z*v.z + v.w*v.w;
    #pragma unroll
    for (int m = 32; m >= 1; m >>= 1) ss += __shfl_xor(ss, m, 64);
    __shared__ float red[4];
    const int wid = tid >> 6, lane = tid & 63;
    if (lane == 0) red[wid] = ss;
    __syncthreads();
    const float tot = red[0] + red[1] + red[2] + red[3];
    const float inv = 1.f / (sqrtf(tot * (1.f / EQ)) + 1e-8f);
    bf16x4 o;
    o[0] = (bf16_t)(v.x * inv); o[1] = (bf16_t)(v.y * inv);
    o[2] = (bf16_t)(v.z * inv); o[3] = (bf16_t)(v.w * inv);
    *(bf16x4*)(xn + (size_t)row * EQ + tid * 4) = o;
}

// ---------------------------------------------------------------- 8-phase GEMM
// C[m,n] = sum_k A[m,k]*B[n,k], BM=256, BN=NREP*64, BK=32.
// 512 threads = 8 waves (2 M x 4 N), wave tile 128 x (NREP*16).
// Triple-buffered LDS, prefetch distance 2 K-tiles, counted vmcnt boundaries.
// XOR-swizzled LDS (g(r)=(r^(r>>2))&3 on 16B slots), both sides.
// XCD-chunked block swizzle (nwg % 8 == 0 required).

template<int NREP, int MODE>   // MODE 0: silu->bf16 row-major   1: silu->bf16 (h,b,hd,t)   2: +bias+res->f32
__global__ __launch_bounds__(512, 1) void gemm8p(
    const bf16_t* __restrict__ A, const bf16_t* __restrict__ Bm,
    int K, int N,
    const float* __restrict__ bias, const float* __restrict__ res,
    bf16_t* __restrict__ Cb, float* __restrict__ Cf)
{
    constexpr int LB      = NREP / 2;            // B loads per K-tile (2 or 1)
    constexpr int BSTRIDE = 16384 + NREP * 4096; // bytes per buffer
    __shared__ alignas(16) char smem[3 * BSTRIDE];

    // XCD-chunked bijective swizzle
    const int nwg   = gridDim.x * gridDim.y;
    const int bid   = blockIdx.y * gridDim.x + blockIdx.x;
    const int chunk = nwg >> 3;
    const int sb    = (bid & 7) * chunk + (bid >> 3);
    const int bx    = sb % gridDim.x;
    const int by    = sb / gridDim.x;

    const int tid  = threadIdx.x;
    const int wid  = tid >> 6;
    const int lane = tid & 63;
    const int frow = lane & 15;
    const int c    = lane >> 4;
    const int m0 = by * 256;
    const int n0 = bx * (NREP * 64);
    const int wrm = (wid >> 2) * 128;
    const int wrn = (wid & 3) * (NREP * 16);

    const int Ra = wrm + frow;
    const int ga = (Ra ^ (Ra >> 2)) & 3;
    const int offA = Ra * 64 + ((c ^ ga) << 4);
    const int Rb = wrn + frow;
    const int gb = (Rb ^ (Rb >> 2)) & 3;
    const int offB = 16384 + Rb * 64 + ((c ^ gb) << 4);

    const int sr   = tid >> 2;
    const int slot = tid & 3;
    const int gs   = (sr ^ (sr >> 2)) & 3;
    const size_t lda = (size_t)K * 2;
    const char* srcA  = (const char*)A  + (size_t)(m0 + sr) * lda + ((slot ^ gs) << 4);
    const char* srcA2 = srcA + 128 * lda;
    const char* srcB  = (const char*)Bm + (size_t)(n0 + sr) * lda + ((slot ^ gs) << 4);
    const char* srcB2 = srcB + 128 * lda;

    auto STAGE_A = [&](int buf, int kt) {
        char* d = smem + buf * BSTRIDE + wid * 1024;
        __builtin_amdgcn_global_load_lds(GAS1(srcA  + (size_t)kt * 64), LAS3(d), 16, 0, 0);
        __builtin_amdgcn_global_load_lds(GAS1(srcA2 + (size_t)kt * 64), LAS3(d + 8192), 16, 0, 0);
    };
    auto STAGE_B = [&](int buf, int kt) {
        char* d = smem + buf * BSTRIDE + 16384 + wid * 1024;
        __builtin_amdgcn_global_load_lds(GAS1(srcB  + (size_t)kt * 64), LAS3(d), 16, 0, 0);
        if constexpr (LB == 2)
            __builtin_amdgcn_global_load_lds(GAS1(srcB2 + (size_t)kt * 64), LAS3(d + 8192), 16, 0, 0);
    };

    f32x4 acc[8][NREP];
    #pragma unroll
    for (int i = 0; i < 8; ++i)
        #pragma unroll
        for (int j = 0; j < NREP; ++j) acc[i][j] = (f32x4){0.f, 0.f, 0.f, 0.f};

    const int NT = K >> 5;

    STAGE_A(0, 0); STAGE_B(0, 0);
    STAGE_A(1, 1); STAGE_B(1, 1);
    if constexpr (LB == 2) asm volatile("s_waitcnt vmcnt(4)" ::: "memory");
    else                   asm volatile("s_waitcnt vmcnt(3)" ::: "memory");
    __builtin_amdgcn_s_barrier();

    int buf = 0;
    for (int kq = 0; kq < NT; ++kq) {
        const char* base = smem + buf * BSTRIDE;
        int pbuf = buf + 2; if (pbuf >= 3) pbuf -= 3;
        const bool pf = (kq < NT - 2);

        bf16x8 av[4], bv[NREP];
        #pragma unroll
        for (int i = 0; i < 4; ++i)
            av[i] = *(const bf16x8*)(base + offA + i * 1024);
        #pragma unroll
        for (int i = 0; i < NREP; ++i)
            bv[i] = *(const bf16x8*)(base + offB + i * 1024);
        if (pf) STAGE_A(pbuf, kq + 2);
        __builtin_amdgcn_s_barrier();
        __builtin_amdgcn_s_setprio(1);
        #pragma unroll
        for (int mi = 0; mi < 4; ++mi)
            #pragma unroll
            for (int ni = 0; ni < NREP; ++ni)
                acc[mi][ni] = __builtin_amdgcn_mfma_f32_16x16x32_bf16(
                    av[mi], bv[ni], acc[mi][ni], 0, 0, 0);
        __builtin_amdgcn_s_setprio(0);
        __builtin_amdgcn_sched_barrier(0);
        __builtin_amdgcn_s_barrier();

        #pragma unroll
        for (int i = 0; i < 4; ++i)
            av[i] = *(const bf16x8*)(base + offA + (4 + i) * 1024);
        if (pf) STAGE_B(pbuf, kq + 2);
        __builtin_amdgcn_s_barrier();
        __builtin_amdgcn_s_setprio(1);
        #pragma unroll
        for (int mi = 0; mi < 4; ++mi)
            #pragma unroll
            for (int ni = 0; ni < NREP; ++ni)
                acc[4 + mi][ni] = __builtin_amdgcn_mfma_f32_16x16x32_bf16(
                    av[mi], bv[ni], acc[4 + mi][ni], 0, 0, 0);
        __builtin_amdgcn_s_setprio(0);
        __builtin_amdgcn_sched_barrier(0);

        if (kq < NT - 1) {
            if (kq <= NT - 3) {
                if constexpr (LB == 2) asm volatile("s_waitcnt vmcnt(4)" ::: "memory");
                else                   asm volatile("s_waitcnt vmcnt(3)" ::: "memory");
            } else {
                asm volatile("s_waitcnt vmcnt(0)" ::: "memory");
            }
            __builtin_amdgcn_s_barrier();
        }
        buf = (buf == 2) ? 0 : buf + 1;
    }

    // epilogue: C/D layout col(n)=frow, row(m)=c*4+j
    const int fq = c * 4;
    #pragma unroll
    for (int mi = 0; mi < 8; ++mi) {
        #pragma unroll
        for (int ni = 0; ni < NREP; ++ni) {
            const int gn = n0 + wrn + ni * 16 + frow;
            #pragma unroll
            for (int j = 0; j < 4; ++j) {
                const int gm = m0 + wrm + mi * 16 + fq + j;
                float v = acc[mi][ni][j];
                if constexpr (MODE == 0) {
                    v += bias[gn];
                    v = v / (1.f + __expf(-v));
                    Cb[(size_t)gm * N + gn] = (bf16_t)v;
                } else if constexpr (MODE == 1) {
                    v += bias[gn];
                    v = v / (1.f + __expf(-v));
                    // write transposed: (h, b, hd, t);  gm = t*4+b, gn = h*256+hd
                    const int t = gm >> 2, b2 = gm & 3;
                    const int hh = gn >> 8, hd = gn & 255;
                    Cb[(((size_t)hh * 4 + b2) * 256 + hd) * LQ + t] = (bf16_t)v;
                } else {
                    v += bias[gn] + res[(size_t)gm * N + gn];
                    Cf[(size_t)gm * N + gn] = v;
                }
            }
        }
    }
}

// ---------------------------------------------------------------- Toeplitz GEMM, 8-phase
// Per head h: out[t, n] = sum_s T_h[t,s] * VT[h][n][s], n = b*256+hd (N=1024).
// BM=128, BN=256, BK=32; 8 waves (2M x 4N), wave tile 64x64, acc[4][4].
// A staged from precomputed 128x32 Toeplitz tiles; causal K-loop (NT=4*m_blk+4).
// Heavy-first 1-D grid of 512 blocks; triple-buffered swizzled LDS (72 KB).
__global__ __launch_bounds__(512, 4) void gemm_toep8p(
    const bf16_t* __restrict__ VT, const bf16_t* __restrict__ Atiles,
    const bf16_t* __restrict__ U, bf16_t* __restrict__ O)
{
    constexpr int BSTRIDE = 24576;   // A 8KB + B 16KB
    __shared__ alignas(16) char smem[3 * BSTRIDE];

    const int bid   = blockIdx.x;          // 0..511
    const int m_blk = 15 - (bid >> 5);     // heavy-first
    const int sub   = bid & 31;
    const int h     = sub >> 2;
    const int n0    = (sub & 3) * 256;
    const int m0    = m_blk * 128;

    const int tid  = threadIdx.x;
    const int wid  = tid >> 6;
    const int lane = tid & 63;
    const int frow = lane & 15;
    const int c    = lane >> 4;
    const int wrm  = (wid >> 2) * 64;
    const int wrn  = (wid & 3) * 64;

    const int Ra = wrm + frow;
    const int ga = (Ra ^ (Ra >> 2)) & 3;
    const int offA = Ra * 64 + ((c ^ ga) << 4);
    const int Rb = wrn + frow;
    const int gb = (Rb ^ (Rb >> 2)) & 3;
    const int offB = 8192 + Rb * 64 + ((c ^ gb) << 4);

    const int sr   = tid >> 2;
    const int slot = tid & 3;
    const int gs   = (sr ^ (sr >> 2)) & 3;
    const int soff = (slot ^ gs) << 4;

    const char* Ah = (const char*)(Atiles + (size_t)h * 64 * 4096);
    const size_t ldb = (size_t)LQ * 2;
    const char* srcB  = (const char*)VT + ((size_t)h * 1024 + n0 + sr) * ldb + soff;
    const char* srcB2 = srcB + 128 * ldb;

    auto STAGE_A = [&](int buf, int kt) {
        const int q = 4 * m_blk + 3 - kt;
        const char* s = Ah + (size_t)q * 8192 + (size_t)sr * 64 + soff;
        __builtin_amdgcn_global_load_lds(GAS1(s),
                                         LAS3(smem + buf * BSTRIDE + wid * 1024), 16, 0, 0);
    };
    auto STAGE_B = [&](int buf, int kt) {
        char* d = smem + buf * BSTRIDE + 8192 + wid * 1024;
        __builtin_amdgcn_global_load_lds(GAS1(srcB  + (size_t)kt * 64), LAS3(d), 16, 0, 0);
        __builtin_amdgcn_global_load_lds(GAS1(srcB2 + (size_t)kt * 64), LAS3(d + 8192), 16, 0, 0);
    };

    f32x4 acc[4][4];
    #pragma unroll
    for (int i = 0; i < 4; ++i)
        #pragma unroll
        for (int j = 0; j < 4; ++j) acc[i][j] = (f32x4){0.f, 0.f, 0.f, 0.f};

    const int NT = 4 * m_blk + 4;          // causal K-tiles

    STAGE_A(0, 0); STAGE_B(0, 0);
    STAGE_A(1, 1); STAGE_B(1, 1);
    asm volatile("s_waitcnt vmcnt(3)" ::: "memory");
    __builtin_amdgcn_s_barrier();

    int buf = 0;
    for (int kq = 0; kq < NT; ++kq) {
        const char* base = smem + buf * BSTRIDE;
        int pbuf = buf + 2; if (pbuf >= 3) pbuf -= 3;
        const bool pf = (kq < NT - 2);

        bf16x8 av[4], bv[4];
        #pragma unroll
        for (int i = 0; i < 4; ++i)
            av[i] = *(const bf16x8*)(base + offA + i * 1024);
        #pragma unroll
        for (int i = 0; i < 2; ++i)
            bv[i] = *(const bf16x8*)(base + offB + i * 1024);
        if (pf) STAGE_A(pbuf, kq + 2);
        __builtin_amdgcn_s_barrier();
        __builtin_amdgcn_s_setprio(1);
        #pragma unroll
        for (int mi = 0; mi < 4; ++mi)
            #pragma unroll
            for (int ni = 0; ni < 2; ++ni)
                acc[mi][ni] = __builtin_amdgcn_mfma_f32_16x16x32_bf16(
                    av[mi], bv[ni], acc[mi][ni], 0, 0, 0);
        __builtin_amdgcn_s_setprio(0);
        __builtin_amdgcn_sched_barrier(0);
        __builtin_amdgcn_s_barrier();

        #pragma unroll
        for (int i = 2; i < 4; ++i)
            bv[i] = *(const bf16x8*)(base + offB + i * 1024);
        if (pf) STAGE_B(pbuf, kq + 2);
        __builtin_amdgcn_s_barrier();
        __builtin_amdgcn_s_setprio(1);
        #pragma unroll
        for (int mi = 0; mi < 4; ++mi)
            #pragma unroll
            for (int ni = 2; ni < 4; ++ni)
                acc[mi][ni] = __builtin_amdgcn_mfma_f32_16x16x32_bf16(
                    av[mi], bv[ni], acc[mi][ni], 0, 0, 0);
        __builtin_amdgcn_s_setprio(0);
        __builtin_amdgcn_sched_barrier(0);

        if (kq < NT - 1) {
            if (kq <= NT - 3) asm volatile("s_waitcnt vmcnt(3)" ::: "memory");
            else              asm volatile("s_waitcnt vmcnt(0)" ::: "memory");
            __builtin_amdgcn_s_barrier();
        }
        buf = (buf == 2) ? 0 : buf + 1;
    }

    // epilogue: gate with U and scatter to (t*4+b, h*256+hd)
    const int fq = c * 4;
    #pragma unroll
    for (int mi = 0; mi < 4; ++mi) {
        #pragma unroll
        for (int ni = 0; ni < 4; ++ni) {
            const int nn = n0 + wrn + ni * 16 + frow;   // 0..1023
            const int b  = nn >> 8, hd = nn & 255;
            #pragma unroll
            for (int j = 0; j < 4; ++j) {
                const int t = m0 + wrm + mi * 16 + fq + j;
                const size_t idx = ((size_t)t * BQ + b) * D1Q + h * HDQ + hd;
                const float uval = (float)U[idx];
                O[idx] = (bf16_t)(uval * acc[mi][ni][j]);
            }
        }
    }
}

// ---------------------------------------------------------------- launch

extern "C" void kernel_launch(void* const* d_in, const int* in_sizes, int n_in,
                              void* d_out, int out_size, void* d_ws, size_t ws_size,
                              hipStream_t stream)
{
    const float* x    = (const float*)d_in[0];
    const float* Wu   = (const float*)d_in[1];
    const float* bu   = (const float*)d_in[2];
    const float* Wv   = (const float*)d_in[3];
    const float* bv   = (const float*)d_in[4];
    const float* Wo   = (const float*)d_in[5];
    const float* bo   = (const float*)d_in[6];
    const float* zero = (const float*)d_in[7];
    const float* pos  = (const float*)d_in[8];
    float* out = (float*)d_out;

    char* ws = (char*)d_ws;
    size_t off = 0;
    auto alloc = [&](size_t bytes) {
        char* p = ws + off;
        off += (bytes + 255) & ~(size_t)255;
        return p;
    };
    bf16_t* xn     = (bf16_t*)alloc((size_t)NBQ * EQ * 2);
    bf16_t* Wub    = (bf16_t*)alloc((size_t)D1Q * EQ * 2);
    bf16_t* Wvb    = (bf16_t*)alloc((size_t)D1Q * EQ * 2);
    bf16_t* Wob    = (bf16_t*)alloc((size_t)EQ * D1Q * 2);
    bf16_t* Atiles = (bf16_t*)alloc((size_t)HQ * 64 * 4096 * 2);
    bf16_t* Ub     = (bf16_t*)alloc((size_t)NBQ * D1Q * 2);
    bf16_t* VTb    = (bf16_t*)alloc((size_t)NBQ * D1Q * 2);   // (h,b,hd,t)
    bf16_t* Ob     = (bf16_t*)alloc((size_t)NBQ * D1Q * 2);

    convert_kernel<<<8192, 256, 0, stream>>>(Wu, Wv, Wo, Wub, Wvb, Wob);
    build_toep_tiles<<<dim3(64, 8), 256, 0, stream>>>(zero, pos, Atiles);
    rmsnorm_kernel<<<NBQ, 256, 0, stream>>>(x, xn);

    // U: row-major; V: direct transposed write (h,b,hd,t)
    dim3 g1(D1Q / 256, NBQ / 256);   // (8, 32) = 256 blocks
    gemm8p<4, 0><<<g1, 512, 0, stream>>>(xn, Wub, EQ, D1Q, bu, nullptr, Ub, nullptr);
    gemm8p<4, 1><<<g1, 512, 0, stream>>>(xn, Wvb, EQ, D1Q, bv, nullptr, VTb, nullptr);

    gemm_toep8p<<<512, 512, 0, stream>>>(VTb, Atiles, Ub, Ob);

    // final: M=8192, N=1024, K=2048 — 256x128 tiles, 256 blocks
    dim3 g2(EQ / 128, NBQ / 256);    // (8, 32)
    gemm8p<2, 2><<<g2, 512, 0, stream>>>(Ob, Wob, D1Q, EQ, bo, x, nullptr, out);
}

// Round 5
// 225.579 us; speedup vs baseline: 1.2126x; 1.2126x over previous
//
#include <hip/hip_runtime.h>
#include <cstdint>
#include <cstddef>

#define LQ   2048
#define BQ   4
#define EQ   1024
#define HQ   8
#define D1Q  2048
#define HDQ  256
#define NBQ  (LQ*BQ)   // 8192 rows in (n,b) layout

typedef __bf16 bf16_t;
typedef __bf16 bf16x8 __attribute__((ext_vector_type(8)));
typedef __bf16 bf16x4 __attribute__((ext_vector_type(4)));
typedef float  f32x4  __attribute__((ext_vector_type(4)));

#define GAS1(p) ((const __attribute__((address_space(1))) void*)(p))
#define LAS3(p) ((__attribute__((address_space(3))) void*)(p))

// ---------------------------------------------------------------- utilities

__global__ __launch_bounds__(256) void convert_kernel(
    const float* __restrict__ Wu, const float* __restrict__ Wv,
    const float* __restrict__ Wo,
    bf16_t* __restrict__ Wub, bf16_t* __restrict__ Wvb,
    bf16_t* __restrict__ Wob)
{
    const size_t i = (size_t)blockIdx.x * 256 + threadIdx.x;
    if (i < (size_t)D1Q * EQ) {
        Wub[i] = (bf16_t)Wu[i];
        Wvb[i] = (bf16_t)Wv[i];
        Wob[i] = (bf16_t)Wo[i];
    }
}

// Precompute all Toeplitz A-tiles (128x32, diagonal offset (q-3)*32).
__global__ __launch_bounds__(256) void build_toep_tiles(
    const float* __restrict__ zero, const float* __restrict__ pos,
    bf16_t* __restrict__ Atiles)
{
    const int q = blockIdx.x;        // 0..63
    const int h = blockIdx.y;        // 0..7
    const int doff = (q - 3) * 32;
    const int tid = threadIdx.x;
    bf16_t* dst = Atiles + ((size_t)h * 64 + q) * (128 * 32);
    const int e0 = tid * 16;
    const int r = e0 >> 5;
    const int cbase = e0 & 31;
    bf16_t vals[16];
    #pragma unroll
    for (int j = 0; j < 16; ++j) {
        const int d = doff + r - (cbase + j);
        float v = 0.f;
        if (d == 0) v = zero[h];
        else if (d > 0) v = pos[(size_t)h * (LQ - 1) + d - 1];
        vals[j] = (bf16_t)v;
    }
    *(bf16x8*)(dst + e0)     = *(bf16x8*)(vals);
    *(bf16x8*)(dst + e0 + 8) = *(bf16x8*)(vals + 8);
}

__global__ __launch_bounds__(256) void rmsnorm_kernel(
    const float* __restrict__ x, bf16_t* __restrict__ xn)
{
    const int row = blockIdx.x;           // 0..8191
    const int tid = threadIdx.x;
    const float4 v = ((const float4*)(x + (size_t)row * EQ))[tid];
    float ss = v.x*v.x + v.y*v.y + v.z*v.z + v.w*v.w;
    #pragma unroll
    for (int m = 32; m >= 1; m >>= 1) ss += __shfl_xor(ss, m, 64);
    __shared__ float red[4];
    const int wid = tid >> 6, lane = tid & 63;
    if (lane == 0) red[wid] = ss;
    __syncthreads();
    const float tot = red[0] + red[1] + red[2] + red[3];
    const float inv = 1.f / (sqrtf(tot * (1.f / EQ)) + 1e-8f);
    bf16x4 o;
    o[0] = (bf16_t)(v.x * inv); o[1] = (bf16_t)(v.y * inv);
    o[2] = (bf16_t)(v.z * inv); o[3] = (bf16_t)(v.w * inv);
    *(bf16x4*)(xn + (size_t)row * EQ + tid * 4) = o;
}

// ---------------------------------------------------------------- 8-phase GEMM
// C[m,n] = sum_k A[m,k]*B[n,k], BM=256, BN=NREP*64, BK=32.
// 512 threads = 8 waves (2 M x 4 N), wave tile 128 x (NREP*16).
// Triple-buffered LDS, prefetch distance 2 K-tiles, counted vmcnt boundaries.
// XOR-swizzled LDS (g(r)=(r^(r>>2))&3 on 16B slots), both sides.
// XCD-chunked block swizzle (nwg % 8 == 0 required).
// MODE 0: silu->bf16 row-major
// MODE 1: silu->bf16 written (h,b,hd,t) via LDS-staged per-wave transpose
// MODE 2: +bias+res->f32 row-major

template<int NREP, int MODE>
__global__ __launch_bounds__(512, 1) void gemm8p(
    const bf16_t* __restrict__ A, const bf16_t* __restrict__ Bm,
    int K, int N,
    const float* __restrict__ bias, const float* __restrict__ res,
    bf16_t* __restrict__ Cb, float* __restrict__ Cf)
{
    constexpr int LB      = NREP / 2;            // B loads per K-tile (2 or 1)
    constexpr int BSTRIDE = 16384 + NREP * 4096; // bytes per buffer
    __shared__ alignas(16) char smem[3 * BSTRIDE];

    // XCD-chunked bijective swizzle
    const int nwg   = gridDim.x * gridDim.y;
    const int bid   = blockIdx.y * gridDim.x + blockIdx.x;
    const int chunkw = nwg >> 3;
    const int sb    = (bid & 7) * chunkw + (bid >> 3);
    const int bx    = sb % gridDim.x;
    const int by    = sb / gridDim.x;

    const int tid  = threadIdx.x;
    const int wid  = tid >> 6;
    const int lane = tid & 63;
    const int frow = lane & 15;
    const int c    = lane >> 4;
    const int m0 = by * 256;
    const int n0 = bx * (NREP * 64);
    const int wrm = (wid >> 2) * 128;
    const int wrn = (wid & 3) * (NREP * 16);

    const int Ra = wrm + frow;
    const int ga = (Ra ^ (Ra >> 2)) & 3;
    const int offA = Ra * 64 + ((c ^ ga) << 4);
    const int Rb = wrn + frow;
    const int gb = (Rb ^ (Rb >> 2)) & 3;
    const int offB = 16384 + Rb * 64 + ((c ^ gb) << 4);

    const int sr   = tid >> 2;
    const int slot = tid & 3;
    const int gs   = (sr ^ (sr >> 2)) & 3;
    const size_t lda = (size_t)K * 2;
    const char* srcA  = (const char*)A  + (size_t)(m0 + sr) * lda + ((slot ^ gs) << 4);
    const char* srcA2 = srcA + 128 * lda;
    const char* srcB  = (const char*)Bm + (size_t)(n0 + sr) * lda + ((slot ^ gs) << 4);
    const char* srcB2 = srcB + 128 * lda;

    auto STAGE_A = [&](int buf, int kt) {
        char* d = smem + buf * BSTRIDE + wid * 1024;
        __builtin_amdgcn_global_load_lds(GAS1(srcA  + (size_t)kt * 64), LAS3(d), 16, 0, 0);
        __builtin_amdgcn_global_load_lds(GAS1(srcA2 + (size_t)kt * 64), LAS3(d + 8192), 16, 0, 0);
    };
    auto STAGE_B = [&](int buf, int kt) {
        char* d = smem + buf * BSTRIDE + 16384 + wid * 1024;
        __builtin_amdgcn_global_load_lds(GAS1(srcB  + (size_t)kt * 64), LAS3(d), 16, 0, 0);
        if constexpr (LB == 2)
            __builtin_amdgcn_global_load_lds(GAS1(srcB2 + (size_t)kt * 64), LAS3(d + 8192), 16, 0, 0);
    };

    f32x4 acc[8][NREP];
    #pragma unroll
    for (int i = 0; i < 8; ++i)
        #pragma unroll
        for (int j = 0; j < NREP; ++j) acc[i][j] = (f32x4){0.f, 0.f, 0.f, 0.f};

    const int NT = K >> 5;

    STAGE_A(0, 0); STAGE_B(0, 0);
    STAGE_A(1, 1); STAGE_B(1, 1);
    if constexpr (LB == 2) asm volatile("s_waitcnt vmcnt(4)" ::: "memory");
    else                   asm volatile("s_waitcnt vmcnt(3)" ::: "memory");
    __builtin_amdgcn_s_barrier();

    int buf = 0;
    for (int kq = 0; kq < NT; ++kq) {
        const char* base = smem + buf * BSTRIDE;
        int pbuf = buf + 2; if (pbuf >= 3) pbuf -= 3;
        const bool pf = (kq < NT - 2);

        bf16x8 av[4], bv[NREP];
        #pragma unroll
        for (int i = 0; i < 4; ++i)
            av[i] = *(const bf16x8*)(base + offA + i * 1024);
        #pragma unroll
        for (int i = 0; i < NREP; ++i)
            bv[i] = *(const bf16x8*)(base + offB + i * 1024);
        if (pf) STAGE_A(pbuf, kq + 2);
        __builtin_amdgcn_s_barrier();
        __builtin_amdgcn_s_setprio(1);
        #pragma unroll
        for (int mi = 0; mi < 4; ++mi)
            #pragma unroll
            for (int ni = 0; ni < NREP; ++ni)
                acc[mi][ni] = __builtin_amdgcn_mfma_f32_16x16x32_bf16(
                    av[mi], bv[ni], acc[mi][ni], 0, 0, 0);
        __builtin_amdgcn_s_setprio(0);
        __builtin_amdgcn_sched_barrier(0);
        __builtin_amdgcn_s_barrier();

        #pragma unroll
        for (int i = 0; i < 4; ++i)
            av[i] = *(const bf16x8*)(base + offA + (4 + i) * 1024);
        if (pf) STAGE_B(pbuf, kq + 2);
        __builtin_amdgcn_s_barrier();
        __builtin_amdgcn_s_setprio(1);
        #pragma unroll
        for (int mi = 0; mi < 4; ++mi)
            #pragma unroll
            for (int ni = 0; ni < NREP; ++ni)
                acc[4 + mi][ni] = __builtin_amdgcn_mfma_f32_16x16x32_bf16(
                    av[mi], bv[ni], acc[4 + mi][ni], 0, 0, 0);
        __builtin_amdgcn_s_setprio(0);
        __builtin_amdgcn_sched_barrier(0);

        if (kq < NT - 1) {
            if (kq <= NT - 3) {
                if constexpr (LB == 2) asm volatile("s_waitcnt vmcnt(4)" ::: "memory");
                else                   asm volatile("s_waitcnt vmcnt(3)" ::: "memory");
            } else {
                asm volatile("s_waitcnt vmcnt(0)" ::: "memory");
            }
            __builtin_amdgcn_s_barrier();
        }
        buf = (buf == 2) ? 0 : buf + 1;
    }

    if constexpr (MODE == 1) {
        // LDS-staged transpose epilogue: write (h, b, hd, t) coalesced.
        static_assert(NREP == 4, "MODE 1 requires NREP=4");
        const int hh = n0 >> 8;                 // head (BN=256 == HDQ block)
        float bb[4];
        #pragma unroll
        for (int ni = 0; ni < 4; ++ni) bb[ni] = bias[n0 + wrn + ni * 16 + frow];

        #pragma unroll
        for (int p = 0; p < 2; ++p) {
            __syncthreads();                    // K-loop LDS / prev pass done
            bf16_t* chunk = (bf16_t*)smem + wid * 4608;  // 64 n x [b:16][t:16], stride 72
            #pragma unroll
            for (int mi2 = 0; mi2 < 4; ++mi2) {
                #pragma unroll
                for (int ni = 0; ni < 4; ++ni) {
                    const int nl = ni * 16 + frow;
                    #pragma unroll
                    for (int j = 0; j < 4; ++j) {   // j == b
                        float v = acc[p * 4 + mi2][ni][j] + bb[ni];
                        v = v / (1.f + __expf(-v));
                        chunk[nl * 72 + j * 16 + mi2 * 4 + c] = (bf16_t)v;
                    }
                }
            }
            __syncthreads();
            const int hd = wrn + lane;          // lane owns one hd row
            const int tb = (m0 + wrm + p * 64) >> 2;
            const bf16_t* rowp = chunk + lane * 72;
            #pragma unroll
            for (int b2 = 0; b2 < 4; ++b2) {
                bf16x8 r0 = *(const bf16x8*)(rowp + b2 * 16);
                bf16x8 r1 = *(const bf16x8*)(rowp + b2 * 16 + 8);
                bf16_t* dst = Cb + (((size_t)hh * 4 + b2) * 256 + hd) * (size_t)LQ + tb;
                *(bf16x8*)(dst)     = r0;
                *(bf16x8*)(dst + 8) = r1;
            }
        }
        return;
    }

    // epilogue (MODE 0 / 2): C/D layout col(n)=frow, row(m)=c*4+j
    const int fq = c * 4;
    #pragma unroll
    for (int mi = 0; mi < 8; ++mi) {
        #pragma unroll
        for (int ni = 0; ni < NREP; ++ni) {
            const int gn = n0 + wrn + ni * 16 + frow;
            #pragma unroll
            for (int j = 0; j < 4; ++j) {
                const int gm = m0 + wrm + mi * 16 + fq + j;
                float v = acc[mi][ni][j];
                if constexpr (MODE == 0) {
                    v += bias[gn];
                    v = v / (1.f + __expf(-v));
                    Cb[(size_t)gm * N + gn] = (bf16_t)v;
                } else {
                    v += bias[gn] + res[(size_t)gm * N + gn];
                    Cf[(size_t)gm * N + gn] = v;
                }
            }
        }
    }
}

// ---------------------------------------------------------------- Toeplitz GEMM, 8-phase
// Per head h: out[t, n] = sum_s T_h[t,s] * VT[h][n][s], n = b*256+hd (N=1024).
// BM=128, BN=256, BK=32; 8 waves (2M x 4N), wave tile 64x64, acc[4][4].
// A staged from precomputed 128x32 Toeplitz tiles; causal K-loop (NT=4*m_blk+4).
// Heavy-first 1-D grid of 512 blocks; triple-buffered swizzled LDS (72 KB).
__global__ __launch_bounds__(512, 4) void gemm_toep8p(
    const bf16_t* __restrict__ VT, const bf16_t* __restrict__ Atiles,
    const bf16_t* __restrict__ U, bf16_t* __restrict__ O)
{
    constexpr int BSTRIDE = 24576;   // A 8KB + B 16KB
    __shared__ alignas(16) char smem[3 * BSTRIDE];

    const int bid   = blockIdx.x;          // 0..511
    const int m_blk = 15 - (bid >> 5);     // heavy-first
    const int sub   = bid & 31;
    const int h     = sub >> 2;
    const int n0    = (sub & 3) * 256;
    const int m0    = m_blk * 128;

    const int tid  = threadIdx.x;
    const int wid  = tid >> 6;
    const int lane = tid & 63;
    const int frow = lane & 15;
    const int c    = lane >> 4;
    const int wrm  = (wid >> 2) * 64;
    const int wrn  = (wid & 3) * 64;

    const int Ra = wrm + frow;
    const int ga = (Ra ^ (Ra >> 2)) & 3;
    const int offA = Ra * 64 + ((c ^ ga) << 4);
    const int Rb = wrn + frow;
    const int gb = (Rb ^ (Rb >> 2)) & 3;
    const int offB = 8192 + Rb * 64 + ((c ^ gb) << 4);

    const int sr   = tid >> 2;
    const int slot = tid & 3;
    const int gs   = (sr ^ (sr >> 2)) & 3;
    const int soff = (slot ^ gs) << 4;

    const char* Ah = (const char*)(Atiles + (size_t)h * 64 * 4096);
    const size_t ldb = (size_t)LQ * 2;
    const char* srcB  = (const char*)VT + ((size_t)h * 1024 + n0 + sr) * ldb + soff;
    const char* srcB2 = srcB + 128 * ldb;

    auto STAGE_A = [&](int buf, int kt) {
        const int q = 4 * m_blk + 3 - kt;
        const char* s = Ah + (size_t)q * 8192 + (size_t)sr * 64 + soff;
        __builtin_amdgcn_global_load_lds(GAS1(s),
                                         LAS3(smem + buf * BSTRIDE + wid * 1024), 16, 0, 0);
    };
    auto STAGE_B = [&](int buf, int kt) {
        char* d = smem + buf * BSTRIDE + 8192 + wid * 1024;
        __builtin_amdgcn_global_load_lds(GAS1(srcB  + (size_t)kt * 64), LAS3(d), 16, 0, 0);
        __builtin_amdgcn_global_load_lds(GAS1(srcB2 + (size_t)kt * 64), LAS3(d + 8192), 16, 0, 0);
    };

    f32x4 acc[4][4];
    #pragma unroll
    for (int i = 0; i < 4; ++i)
        #pragma unroll
        for (int j = 0; j < 4; ++j) acc[i][j] = (f32x4){0.f, 0.f, 0.f, 0.f};

    const int NT = 4 * m_blk + 4;          // causal K-tiles

    STAGE_A(0, 0); STAGE_B(0, 0);
    STAGE_A(1, 1); STAGE_B(1, 1);
    asm volatile("s_waitcnt vmcnt(3)" ::: "memory");
    __builtin_amdgcn_s_barrier();

    int buf = 0;
    for (int kq = 0; kq < NT; ++kq) {
        const char* base = smem + buf * BSTRIDE;
        int pbuf = buf + 2; if (pbuf >= 3) pbuf -= 3;
        const bool pf = (kq < NT - 2);

        bf16x8 av[4], bv[4];
        #pragma unroll
        for (int i = 0; i < 4; ++i)
            av[i] = *(const bf16x8*)(base + offA + i * 1024);
        #pragma unroll
        for (int i = 0; i < 2; ++i)
            bv[i] = *(const bf16x8*)(base + offB + i * 1024);
        if (pf) STAGE_A(pbuf, kq + 2);
        __builtin_amdgcn_s_barrier();
        __builtin_amdgcn_s_setprio(1);
        #pragma unroll
        for (int mi = 0; mi < 4; ++mi)
            #pragma unroll
            for (int ni = 0; ni < 2; ++ni)
                acc[mi][ni] = __builtin_amdgcn_mfma_f32_16x16x32_bf16(
                    av[mi], bv[ni], acc[mi][ni], 0, 0, 0);
        __builtin_amdgcn_s_setprio(0);
        __builtin_amdgcn_sched_barrier(0);
        __builtin_amdgcn_s_barrier();

        #pragma unroll
        for (int i = 2; i < 4; ++i)
            bv[i] = *(const bf16x8*)(base + offB + i * 1024);
        if (pf) STAGE_B(pbuf, kq + 2);
        __builtin_amdgcn_s_barrier();
        __builtin_amdgcn_s_setprio(1);
        #pragma unroll
        for (int mi = 0; mi < 4; ++mi)
            #pragma unroll
            for (int ni = 2; ni < 4; ++ni)
                acc[mi][ni] = __builtin_amdgcn_mfma_f32_16x16x32_bf16(
                    av[mi], bv[ni], acc[mi][ni], 0, 0, 0);
        __builtin_amdgcn_s_setprio(0);
        __builtin_amdgcn_sched_barrier(0);

        if (kq < NT - 1) {
            if (kq <= NT - 3) asm volatile("s_waitcnt vmcnt(3)" ::: "memory");
            else              asm volatile("s_waitcnt vmcnt(0)" ::: "memory");
            __builtin_amdgcn_s_barrier();
        }
        buf = (buf == 2) ? 0 : buf + 1;
    }

    // epilogue: gate with U and scatter to (t*4+b, h*256+hd)
    const int fq = c * 4;
    #pragma unroll
    for (int mi = 0; mi < 4; ++mi) {
        #pragma unroll
        for (int ni = 0; ni < 4; ++ni) {
            const int nn = n0 + wrn + ni * 16 + frow;   // 0..1023
            const int b  = nn >> 8, hd = nn & 255;
            #pragma unroll
            for (int j = 0; j < 4; ++j) {
                const int t = m0 + wrm + mi * 16 + fq + j;
                const size_t idx = ((size_t)t * BQ + b) * D1Q + h * HDQ + hd;
                const float uval = (float)U[idx];
                O[idx] = (bf16_t)(uval * acc[mi][ni][j]);
            }
        }
    }
}

// ---------------------------------------------------------------- launch

extern "C" void kernel_launch(void* const* d_in, const int* in_sizes, int n_in,
                              void* d_out, int out_size, void* d_ws, size_t ws_size,
                              hipStream_t stream)
{
    const float* x    = (const float*)d_in[0];
    const float* Wu   = (const float*)d_in[1];
    const float* bu   = (const float*)d_in[2];
    const float* Wv   = (const float*)d_in[3];
    const float* bv   = (const float*)d_in[4];
    const float* Wo   = (const float*)d_in[5];
    const float* bo   = (const float*)d_in[6];
    const float* zero = (const float*)d_in[7];
    const float* pos  = (const float*)d_in[8];
    float* out = (float*)d_out;

    char* ws = (char*)d_ws;
    size_t off = 0;
    auto alloc = [&](size_t bytes) {
        char* p = ws + off;
        off += (bytes + 255) & ~(size_t)255;
        return p;
    };
    bf16_t* xn     = (bf16_t*)alloc((size_t)NBQ * EQ * 2);
    bf16_t* Wub    = (bf16_t*)alloc((size_t)D1Q * EQ * 2);
    bf16_t* Wvb    = (bf16_t*)alloc((size_t)D1Q * EQ * 2);
    bf16_t* Wob    = (bf16_t*)alloc((size_t)EQ * D1Q * 2);
    bf16_t* Atiles = (bf16_t*)alloc((size_t)HQ * 64 * 4096 * 2);
    bf16_t* Ub     = (bf16_t*)alloc((size_t)NBQ * D1Q * 2);
    bf16_t* VTb    = (bf16_t*)alloc((size_t)NBQ * D1Q * 2);   // (h,b,hd,t)
    bf16_t* Ob     = (bf16_t*)alloc((size_t)NBQ * D1Q * 2);

    convert_kernel<<<8192, 256, 0, stream>>>(Wu, Wv, Wo, Wub, Wvb, Wob);
    build_toep_tiles<<<dim3(64, 8), 256, 0, stream>>>(zero, pos, Atiles);
    rmsnorm_kernel<<<NBQ, 256, 0, stream>>>(x, xn);

    // U: row-major; V: transposed write (h,b,hd,t) via LDS-staged epilogue
    dim3 g1(D1Q / 256, NBQ / 256);   // (8, 32) = 256 blocks
    gemm8p<4, 0><<<g1, 512, 0, stream>>>(xn, Wub, EQ, D1Q, bu, nullptr, Ub, nullptr);
    gemm8p<4, 1><<<g1, 512, 0, stream>>>(xn, Wvb, EQ, D1Q, bv, nullptr, VTb, nullptr);

    gemm_toep8p<<<512, 512, 0, stream>>>(VTb, Atiles, Ub, Ob);

    // final: M=8192, N=1024, K=2048 — 256x128 tiles, 256 blocks
    dim3 g2(EQ / 128, NBQ / 256);    // (8, 32)
    gemm8p<2, 2><<<g2, 512, 0, stream>>>(Ob, Wob, D1Q, EQ, bo, x, nullptr, out);
}

// Round 6
// 208.519 us; speedup vs baseline: 1.3118x; 1.0818x over previous
//
#include <hip/hip_runtime.h>
#include <cstdint>
#include <cstddef>

#define LQ   2048
#define BQ   4
#define EQ   1024
#define HQ   8
#define D1Q  2048
#define HDQ  256
#define NBQ  (LQ*BQ)   // 8192 rows in (n,b) layout

typedef __bf16 bf16_t;
typedef __bf16 bf16x8 __attribute__((ext_vector_type(8)));
typedef __bf16 bf16x4 __attribute__((ext_vector_type(4)));
typedef float  f32x4  __attribute__((ext_vector_type(4)));

#define GAS1(p) ((const __attribute__((address_space(1))) void*)(p))
#define LAS3(p) ((__attribute__((address_space(3))) void*)(p))

// ---------------------------------------------------------------- utilities

__global__ __launch_bounds__(256) void convert_kernel(
    const float* __restrict__ Wu, const float* __restrict__ Wv,
    const float* __restrict__ Wo,
    bf16_t* __restrict__ Wub, bf16_t* __restrict__ Wvb,
    bf16_t* __restrict__ Wob)
{
    const size_t i = (size_t)blockIdx.x * 256 + threadIdx.x;
    if (i < (size_t)D1Q * EQ) {
        Wub[i] = (bf16_t)Wu[i];
        Wvb[i] = (bf16_t)Wv[i];
        Wob[i] = (bf16_t)Wo[i];
    }
}

// Precompute all Toeplitz A-tiles (128x32, diagonal offset (q-3)*32).
__global__ __launch_bounds__(256) void build_toep_tiles(
    const float* __restrict__ zero, const float* __restrict__ pos,
    bf16_t* __restrict__ Atiles)
{
    const int q = blockIdx.x;        // 0..63
    const int h = blockIdx.y;        // 0..7
    const int doff = (q - 3) * 32;
    const int tid = threadIdx.x;
    bf16_t* dst = Atiles + ((size_t)h * 64 + q) * (128 * 32);
    const int e0 = tid * 16;
    const int r = e0 >> 5;
    const int cbase = e0 & 31;
    bf16_t vals[16];
    #pragma unroll
    for (int j = 0; j < 16; ++j) {
        const int d = doff + r - (cbase + j);
        float v = 0.f;
        if (d == 0) v = zero[h];
        else if (d > 0) v = pos[(size_t)h * (LQ - 1) + d - 1];
        vals[j] = (bf16_t)v;
    }
    *(bf16x8*)(dst + e0)     = *(bf16x8*)(vals);
    *(bf16x8*)(dst + e0 + 8) = *(bf16x8*)(vals + 8);
}

__global__ __launch_bounds__(256) void rmsnorm_kernel(
    const float* __restrict__ x, bf16_t* __restrict__ xn)
{
    const int row = blockIdx.x;           // 0..8191
    const int tid = threadIdx.x;
    const float4 v = ((const float4*)(x + (size_t)row * EQ))[tid];
    float ss = v.x*v.x + v.y*v.y + v.z*v.z + v.w*v.w;
    #pragma unroll
    for (int m = 32; m >= 1; m >>= 1) ss += __shfl_xor(ss, m, 64);
    __shared__ float red[4];
    const int wid = tid >> 6, lane = tid & 63;
    if (lane == 0) red[wid] = ss;
    __syncthreads();
    const float tot = red[0] + red[1] + red[2] + red[3];
    const float inv = 1.f / (sqrtf(tot * (1.f / EQ)) + 1e-8f);
    bf16x4 o;
    o[0] = (bf16_t)(v.x * inv); o[1] = (bf16_t)(v.y * inv);
    o[2] = (bf16_t)(v.z * inv); o[3] = (bf16_t)(v.w * inv);
    *(bf16x4*)(xn + (size_t)row * EQ + tid * 4) = o;
}

// ---------------------------------------------------------------- BK=64 pipelined GEMM
// C[m,n] = sum_k A[m,k]*B[n,k].  BM = 256, BN = WN*64 (NI=4 frags/wave in n).
// 512 threads = 8 waves (WM x WN).  Wave tile (MI*16) x 64.
// BK=64: LDS rows of 128 B, 8 slots of 16 B, slot XOR-swizzled by (row&7),
// both sides (pre-swizzled global source for global_load_lds + swizzled read).
// 2 LDS buffers; tile t+1 staged during tile t (A in phase 0, B in phase 1),
// boundary vmcnt(0) covered by >=2 MFMA phases.  No sched_barrier (m141).
// MODE 0: silu->bf16 row-major   1: silu->bf16 (h,b,hd,t) LDS-transposed
// MODE 2: +bias+res->f32 row-major

template<int MI, int WM, int WN, int MODE>
__global__ __launch_bounds__(512, 2) void gemm8p(
    const bf16_t* __restrict__ A, const bf16_t* __restrict__ Bm,
    int K, int N,
    const float* __restrict__ bias, const float* __restrict__ res,
    bf16_t* __restrict__ Cb, float* __restrict__ Cf)
{
    constexpr int BM = WM * MI * 16;          // 256
    constexpr int BN = WN * 64;               // 256 or 128
    constexpr int ABYTES = BM * 128;          // 32 KB
    constexpr int BBYTES = BN * 128;          // 32/16 KB
    constexpr int BSTRIDE = ABYTES + BBYTES;
    constexpr int CA = BM / 64;               // staging calls for A (4)
    constexpr int CB = BN / 64;               // staging calls for B (4 or 2)
    constexpr int NPH = 2 * (MI / 4);         // phases per K-tile
    static_assert(BM == 256, "staging assumes BM=256");
    static_assert(MODE != 1 || (MI == 8 && WN == 4), "MODE1 geometry");
    __shared__ alignas(16) char smem[2 * BSTRIDE];

    // XCD-chunked bijective swizzle (nwg % 8 == 0)
    const int nwg   = gridDim.x * gridDim.y;
    const int bid   = blockIdx.y * gridDim.x + blockIdx.x;
    const int chunkw = nwg >> 3;
    const int sb    = (bid & 7) * chunkw + (bid >> 3);
    const int bx    = sb % gridDim.x;
    const int by    = sb / gridDim.x;

    const int tid  = threadIdx.x;
    const int wid  = tid >> 6;
    const int lane = tid & 63;
    const int frow = lane & 15;
    const int c    = lane >> 4;
    const int m0 = by * BM;
    const int n0 = bx * BN;
    const int wm = wid / WN, wn = wid % WN;
    const int wrm = wm * (MI * 16);
    const int wrn = wn * 64;

    // fragment-read byte offsets: row*128 + (((kk*4+c) ^ (frow&7))<<4)
    const int g = frow & 7;
    const int offA0 = (wrm + frow) * 128 + ((c ^ g) << 4);
    const int offA1 = offA0 ^ 64;
    const int offB0 = (wrn + frow) * 128 + ((c ^ g) << 4);
    const int offB1 = offB0 ^ 64;

    // staging: thread t covers LDS bytes [cl*8192 + t*16, +16)
    const int rl = tid >> 3;                  // row 0..63 (+cl*64)
    const int ps = tid & 7;
    const int ls = ps ^ (rl & 7);             // pre-swizzled source slot
    const size_t lda2 = (size_t)K * 2;
    const char* sA = (const char*)A  + (size_t)(m0 + rl) * lda2 + ls * 16;
    const char* sB = (const char*)Bm + (size_t)(n0 + rl) * lda2 + ls * 16;

    auto STAGE_A = [&](int bf, int kt) {
        char* d = smem + bf * BSTRIDE + wid * 1024;
        #pragma unroll
        for (int cl = 0; cl < CA; ++cl)
            __builtin_amdgcn_global_load_lds(
                GAS1(sA + (size_t)cl * 64 * lda2 + (size_t)kt * 128),
                LAS3(d + cl * 8192), 16, 0, 0);
    };
    auto STAGE_B = [&](int bf, int kt) {
        char* d = smem + bf * BSTRIDE + ABYTES + wid * 1024;
        #pragma unroll
        for (int cl = 0; cl < CB; ++cl)
            __builtin_amdgcn_global_load_lds(
                GAS1(sB + (size_t)cl * 64 * lda2 + (size_t)kt * 128),
                LAS3(d + cl * 8192), 16, 0, 0);
    };

    f32x4 acc[MI][4];
    #pragma unroll
    for (int i = 0; i < MI; ++i)
        #pragma unroll
        for (int j = 0; j < 4; ++j) acc[i][j] = (f32x4){0.f, 0.f, 0.f, 0.f};

    const int NT = K >> 6;

    STAGE_A(0, 0); STAGE_B(0, 0);
    asm volatile("s_waitcnt vmcnt(0)" ::: "memory");
    __builtin_amdgcn_s_barrier();

    int buf = 0;
    for (int t = 0; t < NT; ++t) {
        const char* bA = smem + buf * BSTRIDE;
        const char* bB = bA + ABYTES;
        const bool pf = (t + 1 < NT);
        const int nb = buf ^ 1;
        bf16x8 av[4], bv[4];

        #pragma unroll
        for (int kk = 0; kk < 2; ++kk) {
            #pragma unroll
            for (int mh = 0; mh < MI / 4; ++mh) {
                constexpr int MH = MI / 4;
                const int p = kk * MH + mh;
                #pragma unroll
                for (int i = 0; i < 4; ++i)
                    av[i] = *(const bf16x8*)(bA + (mh * 4 + i) * 2048 + (kk ? offA1 : offA0));
                if (mh == 0) {
                    #pragma unroll
                    for (int i = 0; i < 4; ++i)
                        bv[i] = *(const bf16x8*)(bB + i * 2048 + (kk ? offB1 : offB0));
                }
                if (pf && p == 0) STAGE_A(nb, t + 1);
                if (pf && p == 1) STAGE_B(nb, t + 1);
                __builtin_amdgcn_s_barrier();
                __builtin_amdgcn_s_setprio(1);
                #pragma unroll
                for (int i = 0; i < 4; ++i)
                    #pragma unroll
                    for (int ni = 0; ni < 4; ++ni)
                        acc[mh * 4 + i][ni] = __builtin_amdgcn_mfma_f32_16x16x32_bf16(
                            av[i], bv[ni], acc[mh * 4 + i][ni], 0, 0, 0);
                __builtin_amdgcn_s_setprio(0);
                if (p == NPH - 1) {
                    if (pf) asm volatile("s_waitcnt vmcnt(0)" ::: "memory");
                }
                __builtin_amdgcn_s_barrier();
            }
        }
        buf ^= 1;
    }

    if constexpr (MODE == 1) {
        // LDS-staged transpose epilogue -> (h, b, hd, t), full 64-B t-runs.
        const int hh = n0 >> 8;
        float bb[4];
        #pragma unroll
        for (int ni = 0; ni < 4; ++ni) bb[ni] = bias[n0 + wrn + ni * 16 + frow];

        #pragma unroll
        for (int p = 0; p < 2; ++p) {          // ni-pair halves
            __syncthreads();
            bf16_t* chunk = (bf16_t*)smem + wid * 4224;  // 32 n x [b:4][t:32], stride 132
            #pragma unroll
            for (int mi = 0; mi < 8; ++mi) {
                #pragma unroll
                for (int nio = 0; nio < 2; ++nio) {
                    const int ni = p * 2 + nio;
                    const int nl = nio * 16 + frow;
                    #pragma unroll
                    for (int j = 0; j < 4; ++j) {   // j == b
                        float v = acc[mi][ni][j] + bb[ni];
                        v = v / (1.f + __expf(-v));
                        chunk[nl * 132 + j * 32 + mi * 4 + c] = (bf16_t)v;
                    }
                }
            }
            __syncthreads();
            const int nl  = lane & 31;
            const int bh2 = lane >> 5;
            const int hd  = wrn + p * 32 + nl;
            const int t0  = (m0 + wrm) >> 2;
            #pragma unroll
            for (int bi = 0; bi < 2; ++bi) {
                const int b2 = bh2 * 2 + bi;
                const bf16_t* src = chunk + nl * 132 + b2 * 32;
                bf16_t* dst = Cb + (((size_t)hh * 4 + b2) * 256 + hd) * (size_t)LQ + t0;
                #pragma unroll
                for (int q = 0; q < 4; ++q)
                    *(bf16x8*)(dst + q * 8) = *(const bf16x8*)(src + q * 8);
            }
        }
        return;
    }

    // epilogue (MODE 0 / 2): C/D layout col(n)=frow, row(m)=c*4+j
    const int fq = c * 4;
    #pragma unroll
    for (int mi = 0; mi < MI; ++mi) {
        #pragma unroll
        for (int ni = 0; ni < 4; ++ni) {
            const int gn = n0 + wrn + ni * 16 + frow;
            #pragma unroll
            for (int j = 0; j < 4; ++j) {
                const int gm = m0 + wrm + mi * 16 + fq + j;
                float v = acc[mi][ni][j];
                if constexpr (MODE == 0) {
                    v += bias[gn];
                    v = v / (1.f + __expf(-v));
                    Cb[(size_t)gm * N + gn] = (bf16_t)v;
                } else {
                    v += bias[gn] + res[(size_t)gm * N + gn];
                    Cf[(size_t)gm * N + gn] = v;
                }
            }
        }
    }
}

// ---------------------------------------------------------------- Toeplitz GEMM, 8-phase
// (R5 structure, sched_barrier removed.)  Per head h: out[t,n] = sum_s T_h[t,s]*VT[h][n][s].
__global__ __launch_bounds__(512, 4) void gemm_toep8p(
    const bf16_t* __restrict__ VT, const bf16_t* __restrict__ Atiles,
    const bf16_t* __restrict__ U, bf16_t* __restrict__ O)
{
    constexpr int BSTRIDE = 24576;   // A 8KB + B 16KB
    __shared__ alignas(16) char smem[3 * BSTRIDE];

    const int bid   = blockIdx.x;          // 0..511
    const int m_blk = 15 - (bid >> 5);     // heavy-first
    const int sub   = bid & 31;
    const int h     = sub >> 2;
    const int n0    = (sub & 3) * 256;
    const int m0    = m_blk * 128;

    const int tid  = threadIdx.x;
    const int wid  = tid >> 6;
    const int lane = tid & 63;
    const int frow = lane & 15;
    const int c    = lane >> 4;
    const int wrm  = (wid >> 2) * 64;
    const int wrn  = (wid & 3) * 64;

    const int Ra = wrm + frow;
    const int ga = (Ra ^ (Ra >> 2)) & 3;
    const int offA = Ra * 64 + ((c ^ ga) << 4);
    const int Rb = wrn + frow;
    const int gb = (Rb ^ (Rb >> 2)) & 3;
    const int offB = 8192 + Rb * 64 + ((c ^ gb) << 4);

    const int sr   = tid >> 2;
    const int slot = tid & 3;
    const int gs   = (sr ^ (sr >> 2)) & 3;
    const int soff = (slot ^ gs) << 4;

    const char* Ah = (const char*)(Atiles + (size_t)h * 64 * 4096);
    const size_t ldb = (size_t)LQ * 2;
    const char* srcB  = (const char*)VT + ((size_t)h * 1024 + n0 + sr) * ldb + soff;
    const char* srcB2 = srcB + 128 * ldb;

    auto STAGE_A = [&](int buf, int kt) {
        const int q = 4 * m_blk + 3 - kt;
        const char* s = Ah + (size_t)q * 8192 + (size_t)sr * 64 + soff;
        __builtin_amdgcn_global_load_lds(GAS1(s),
                                         LAS3(smem + buf * BSTRIDE + wid * 1024), 16, 0, 0);
    };
    auto STAGE_B = [&](int buf, int kt) {
        char* d = smem + buf * BSTRIDE + 8192 + wid * 1024;
        __builtin_amdgcn_global_load_lds(GAS1(srcB  + (size_t)kt * 64), LAS3(d), 16, 0, 0);
        __builtin_amdgcn_global_load_lds(GAS1(srcB2 + (size_t)kt * 64), LAS3(d + 8192), 16, 0, 0);
    };

    f32x4 acc[4][4];
    #pragma unroll
    for (int i = 0; i < 4; ++i)
        #pragma unroll
        for (int j = 0; j < 4; ++j) acc[i][j] = (f32x4){0.f, 0.f, 0.f, 0.f};

    const int NT = 4 * m_blk + 4;          // causal K-tiles

    STAGE_A(0, 0); STAGE_B(0, 0);
    STAGE_A(1, 1); STAGE_B(1, 1);
    asm volatile("s_waitcnt vmcnt(3)" ::: "memory");
    __builtin_amdgcn_s_barrier();

    int buf = 0;
    for (int kq = 0; kq < NT; ++kq) {
        const char* base = smem + buf * BSTRIDE;
        int pbuf = buf + 2; if (pbuf >= 3) pbuf -= 3;
        const bool pf = (kq < NT - 2);

        bf16x8 av[4], bv[4];
        #pragma unroll
        for (int i = 0; i < 4; ++i)
            av[i] = *(const bf16x8*)(base + offA + i * 1024);
        #pragma unroll
        for (int i = 0; i < 2; ++i)
            bv[i] = *(const bf16x8*)(base + offB + i * 1024);
        if (pf) STAGE_A(pbuf, kq + 2);
        __builtin_amdgcn_s_barrier();
        __builtin_amdgcn_s_setprio(1);
        #pragma unroll
        for (int mi = 0; mi < 4; ++mi)
            #pragma unroll
            for (int ni = 0; ni < 2; ++ni)
                acc[mi][ni] = __builtin_amdgcn_mfma_f32_16x16x32_bf16(
                    av[mi], bv[ni], acc[mi][ni], 0, 0, 0);
        __builtin_amdgcn_s_setprio(0);
        __builtin_amdgcn_s_barrier();

        #pragma unroll
        for (int i = 2; i < 4; ++i)
            bv[i] = *(const bf16x8*)(base + offB + i * 1024);
        if (pf) STAGE_B(pbuf, kq + 2);
        __builtin_amdgcn_s_barrier();
        __builtin_amdgcn_s_setprio(1);
        #pragma unroll
        for (int mi = 0; mi < 4; ++mi)
            #pragma unroll
            for (int ni = 2; ni < 4; ++ni)
                acc[mi][ni] = __builtin_amdgcn_mfma_f32_16x16x32_bf16(
                    av[mi], bv[ni], acc[mi][ni], 0, 0, 0);
        __builtin_amdgcn_s_setprio(0);

        if (kq < NT - 1) {
            if (kq <= NT - 3) asm volatile("s_waitcnt vmcnt(3)" ::: "memory");
            else              asm volatile("s_waitcnt vmcnt(0)" ::: "memory");
            __builtin_amdgcn_s_barrier();
        }
        buf = (buf == 2) ? 0 : buf + 1;
    }

    // epilogue: gate with U and scatter to (t*4+b, h*256+hd)
    const int fq = c * 4;
    #pragma unroll
    for (int mi = 0; mi < 4; ++mi) {
        #pragma unroll
        for (int ni = 0; ni < 4; ++ni) {
            const int nn = n0 + wrn + ni * 16 + frow;   // 0..1023
            const int b  = nn >> 8, hd = nn & 255;
            #pragma unroll
            for (int j = 0; j < 4; ++j) {
                const int t = m0 + wrm + mi * 16 + fq + j;
                const size_t idx = ((size_t)t * BQ + b) * D1Q + h * HDQ + hd;
                const float uval = (float)U[idx];
                O[idx] = (bf16_t)(uval * acc[mi][ni][j]);
            }
        }
    }
}

// ---------------------------------------------------------------- launch

extern "C" void kernel_launch(void* const* d_in, const int* in_sizes, int n_in,
                              void* d_out, int out_size, void* d_ws, size_t ws_size,
                              hipStream_t stream)
{
    const float* x    = (const float*)d_in[0];
    const float* Wu   = (const float*)d_in[1];
    const float* bu   = (const float*)d_in[2];
    const float* Wv   = (const float*)d_in[3];
    const float* bv   = (const float*)d_in[4];
    const float* Wo   = (const float*)d_in[5];
    const float* bo   = (const float*)d_in[6];
    const float* zero = (const float*)d_in[7];
    const float* pos  = (const float*)d_in[8];
    float* out = (float*)d_out;

    char* ws = (char*)d_ws;
    size_t off = 0;
    auto alloc = [&](size_t bytes) {
        char* p = ws + off;
        off += (bytes + 255) & ~(size_t)255;
        return p;
    };
    bf16_t* xn     = (bf16_t*)alloc((size_t)NBQ * EQ * 2);
    bf16_t* Wub    = (bf16_t*)alloc((size_t)D1Q * EQ * 2);
    bf16_t* Wvb    = (bf16_t*)alloc((size_t)D1Q * EQ * 2);
    bf16_t* Wob    = (bf16_t*)alloc((size_t)EQ * D1Q * 2);
    bf16_t* Atiles = (bf16_t*)alloc((size_t)HQ * 64 * 4096 * 2);
    bf16_t* Ub     = (bf16_t*)alloc((size_t)NBQ * D1Q * 2);
    bf16_t* VTb    = (bf16_t*)alloc((size_t)NBQ * D1Q * 2);   // (h,b,hd,t)
    bf16_t* Ob     = (bf16_t*)alloc((size_t)NBQ * D1Q * 2);

    convert_kernel<<<8192, 256, 0, stream>>>(Wu, Wv, Wo, Wub, Wvb, Wob);
    build_toep_tiles<<<dim3(64, 8), 256, 0, stream>>>(zero, pos, Atiles);
    rmsnorm_kernel<<<NBQ, 256, 0, stream>>>(x, xn);

    // U: row-major; V: transposed write (h,b,hd,t) via LDS-staged epilogue
    dim3 g1(D1Q / 256, NBQ / 256);   // (8, 32) = 256 blocks
    gemm8p<8, 2, 4, 0><<<g1, 512, 0, stream>>>(xn, Wub, EQ, D1Q, bu, nullptr, Ub, nullptr);
    gemm8p<8, 2, 4, 1><<<g1, 512, 0, stream>>>(xn, Wvb, EQ, D1Q, bv, nullptr, VTb, nullptr);

    gemm_toep8p<<<512, 512, 0, stream>>>(VTb, Atiles, Ub, Ob);

    // final: M=8192, N=1024, K=2048 — BM=256, BN=128, waves 4Mx2N, 256 blocks
    dim3 g2(EQ / 128, NBQ / 256);    // (8, 32)
    gemm8p<4, 4, 2, 2><<<g2, 512, 0, stream>>>(Ob, Wob, D1Q, EQ, bo, x, nullptr, out);
}

// Round 7
// 206.818 us; speedup vs baseline: 1.3226x; 1.0082x over previous
//
#include <hip/hip_runtime.h>
#include <cstdint>
#include <cstddef>

#define LQ   2048
#define BQ   4
#define EQ   1024
#define HQ   8
#define D1Q  2048
#define HDQ  256
#define NBQ  (LQ*BQ)   // 8192 rows in (n,b) layout

typedef __bf16 bf16_t;
typedef __bf16 bf16x8 __attribute__((ext_vector_type(8)));
typedef __bf16 bf16x4 __attribute__((ext_vector_type(4)));
typedef float  f32x4  __attribute__((ext_vector_type(4)));

#define GAS1(p) ((const __attribute__((address_space(1))) void*)(p))
#define LAS3(p) ((__attribute__((address_space(3))) void*)(p))

// ---------------------------------------------------------------- utilities

__global__ __launch_bounds__(256) void convert_kernel(
    const float* __restrict__ Wu, const float* __restrict__ Wv,
    const float* __restrict__ Wo,
    bf16_t* __restrict__ Wub, bf16_t* __restrict__ Wvb,
    bf16_t* __restrict__ Wob)
{
    const size_t i = (size_t)blockIdx.x * 256 + threadIdx.x;
    if (i < (size_t)D1Q * EQ) {
        Wub[i] = (bf16_t)Wu[i];
        Wvb[i] = (bf16_t)Wv[i];
        Wob[i] = (bf16_t)Wo[i];
    }
}

// Precompute all Toeplitz A-tiles (128x32, diagonal offset (q-3)*32).
__global__ __launch_bounds__(256) void build_toep_tiles(
    const float* __restrict__ zero, const float* __restrict__ pos,
    bf16_t* __restrict__ Atiles)
{
    const int q = blockIdx.x;        // 0..63
    const int h = blockIdx.y;        // 0..7
    const int doff = (q - 3) * 32;
    const int tid = threadIdx.x;
    bf16_t* dst = Atiles + ((size_t)h * 64 + q) * (128 * 32);
    const int e0 = tid * 16;
    const int r = e0 >> 5;
    const int cbase = e0 & 31;
    bf16_t vals[16];
    #pragma unroll
    for (int j = 0; j < 16; ++j) {
        const int d = doff + r - (cbase + j);
        float v = 0.f;
        if (d == 0) v = zero[h];
        else if (d > 0) v = pos[(size_t)h * (LQ - 1) + d - 1];
        vals[j] = (bf16_t)v;
    }
    *(bf16x8*)(dst + e0)     = *(bf16x8*)(vals);
    *(bf16x8*)(dst + e0 + 8) = *(bf16x8*)(vals + 8);
}

__global__ __launch_bounds__(256) void rmsnorm_kernel(
    const float* __restrict__ x, bf16_t* __restrict__ xn)
{
    const int row = blockIdx.x;           // 0..8191
    const int tid = threadIdx.x;
    const float4 v = ((const float4*)(x + (size_t)row * EQ))[tid];
    float ss = v.x*v.x + v.y*v.y + v.z*v.z + v.w*v.w;
    #pragma unroll
    for (int m = 32; m >= 1; m >>= 1) ss += __shfl_xor(ss, m, 64);
    __shared__ float red[4];
    const int wid = tid >> 6, lane = tid & 63;
    if (lane == 0) red[wid] = ss;
    __syncthreads();
    const float tot = red[0] + red[1] + red[2] + red[3];
    const float inv = 1.f / (sqrtf(tot * (1.f / EQ)) + 1e-8f);
    bf16x4 o;
    o[0] = (bf16_t)(v.x * inv); o[1] = (bf16_t)(v.y * inv);
    o[2] = (bf16_t)(v.z * inv); o[3] = (bf16_t)(v.w * inv);
    *(bf16x4*)(xn + (size_t)row * EQ + tid * 4) = o;
}

// ---------------------------------------------------------------- BK=32 counted-vmcnt GEMM
// C[m,n] = sum_k A[m,k]*B[n,k].  BM=256, BN=WN*64.  512 threads = 8 waves (WM x WN),
// wave tile (MI*16) x 64, acc[MI][4].
// BK=32: LDS rows 64 B, 4 slots of 16 B, slot XOR-swizzled by g(row)=(row>>1)&3
// (both sides: pre-swizzled global source + swizzled frag read -> conflict-free).
// TRIPLE-buffered LDS, prefetch distance 2 K-tiles, boundary wait = counted
// vmcnt(LPT) (never 0 in steady state), ONE barrier per K-tile (race-free:
// a wave re-stages buf t%3 only after the end-of-t barrier).
// MODE 0: silu->bf16 row-major   1: silu->bf16 (h,b,hd,t) LDS-transposed
// MODE 2: +bias+res->f32 row-major

template<int MI, int WM, int WN, int MODE, int WPB>
__global__ __launch_bounds__(512, WPB) void gemm_p(
    const bf16_t* __restrict__ A, const bf16_t* __restrict__ Bm,
    int K, int N,
    const float* __restrict__ bias, const float* __restrict__ res,
    bf16_t* __restrict__ Cb, float* __restrict__ Cf)
{
    constexpr int BM = WM * MI * 16;          // 256
    constexpr int BN = WN * 64;               // 128 or 256
    constexpr int ABYTES = BM * 64;           // 16 KB
    constexpr int BBYTES = BN * 64;           // 8/16 KB
    constexpr int BSTRIDE = ABYTES + BBYTES;
    constexpr int CB = BN / 128;              // B staging calls (1 or 2)
    static_assert(BM == 256, "staging assumes BM=256");
    static_assert(MODE != 1 || (MI == 8 && WN == 4), "MODE1 geometry");
    __shared__ alignas(16) char smem[3 * BSTRIDE];

    // XCD-chunked bijective swizzle (nwg % 8 == 0)
    const int nwg   = gridDim.x * gridDim.y;
    const int bid0  = blockIdx.y * gridDim.x + blockIdx.x;
    const int chunkw = nwg >> 3;
    const int sb    = (bid0 & 7) * chunkw + (bid0 >> 3);
    const int bx    = sb % gridDim.x;
    const int by    = sb / gridDim.x;

    const int tid  = threadIdx.x;
    const int wid  = tid >> 6;
    const int lane = tid & 63;
    const int frow = lane & 15;
    const int c    = lane >> 4;
    const int m0 = by * BM;
    const int n0 = bx * BN;
    const int wm = wid / WN, wn = wid % WN;
    const int wrm = wm * (MI * 16);
    const int wrn = wn * 64;

    // fragment-read byte offsets (swizzled)
    const int g = (frow >> 1) & 3;
    const int offA0 = (wrm + frow) * 64 + ((c ^ g) << 4);
    const int offB0 = ABYTES + (wrn + frow) * 64 + ((c ^ g) << 4);

    // staging: thread covers LDS 16B unit tid (rows of 64B), pre-swizzled source
    const int rA   = tid >> 2;                // 0..127
    const int soff = (((tid & 3) ^ ((rA >> 1) & 3)) << 4);
    const size_t lda2 = (size_t)K * 2;
    const char* sA = (const char*)A  + (size_t)(m0 + rA) * lda2 + soff;
    const char* sB = (const char*)Bm + (size_t)(n0 + rA) * lda2 + soff;

    auto STAGE = [&](int bf, int kt) {
        char* dA = smem + bf * BSTRIDE + wid * 1024;
        __builtin_amdgcn_global_load_lds(GAS1(sA + (size_t)kt * 64), LAS3(dA), 16, 0, 0);
        __builtin_amdgcn_global_load_lds(GAS1(sA + 128 * lda2 + (size_t)kt * 64),
                                         LAS3(dA + 8192), 16, 0, 0);
        char* dB = smem + bf * BSTRIDE + ABYTES + wid * 1024;
        __builtin_amdgcn_global_load_lds(GAS1(sB + (size_t)kt * 64), LAS3(dB), 16, 0, 0);
        if constexpr (CB == 2)
            __builtin_amdgcn_global_load_lds(GAS1(sB + 128 * lda2 + (size_t)kt * 64),
                                             LAS3(dB + 8192), 16, 0, 0);
    };

    f32x4 acc[MI][4];
    #pragma unroll
    for (int i = 0; i < MI; ++i)
        #pragma unroll
        for (int j = 0; j < 4; ++j) acc[i][j] = (f32x4){0.f, 0.f, 0.f, 0.f};

    const int NT = K >> 5;

    STAGE(0, 0); STAGE(1, 1);
    if constexpr (CB == 1) asm volatile("s_waitcnt vmcnt(3)" ::: "memory");
    else                   asm volatile("s_waitcnt vmcnt(4)" ::: "memory");
    __builtin_amdgcn_s_barrier();

    int cur = 0, pb = 2;
    for (int t = 0; t < NT; ++t) {
        const char* base = smem + cur * BSTRIDE;
        bf16x8 av[MI], bv[4];
        #pragma unroll
        for (int i = 0; i < MI; ++i)
            av[i] = *(const bf16x8*)(base + offA0 + i * 1024);
        #pragma unroll
        for (int i = 0; i < 4; ++i)
            bv[i] = *(const bf16x8*)(base + offB0 + i * 1024);
        if (t + 2 < NT) STAGE(pb, t + 2);
        __builtin_amdgcn_s_setprio(1);
        #pragma unroll
        for (int mi = 0; mi < MI; ++mi)
            #pragma unroll
            for (int ni = 0; ni < 4; ++ni)
                acc[mi][ni] = __builtin_amdgcn_mfma_f32_16x16x32_bf16(
                    av[mi], bv[ni], acc[mi][ni], 0, 0, 0);
        __builtin_amdgcn_s_setprio(0);
        if (t + 1 < NT) {
            if (t + 2 < NT) {
                if constexpr (CB == 1) asm volatile("s_waitcnt vmcnt(3)" ::: "memory");
                else                   asm volatile("s_waitcnt vmcnt(4)" ::: "memory");
            } else {
                asm volatile("s_waitcnt vmcnt(0)" ::: "memory");
            }
            __builtin_amdgcn_s_barrier();
        }
        cur = (cur == 2) ? 0 : cur + 1;
        pb  = (pb  == 2) ? 0 : pb  + 1;
    }

    if constexpr (MODE == 1) {
        // LDS-staged transpose epilogue -> (h, b, hd, t), full 64-B t-runs.
        const int hh = n0 >> 8;
        float bb[4];
        #pragma unroll
        for (int ni = 0; ni < 4; ++ni) bb[ni] = bias[n0 + wrn + ni * 16 + frow];

        #pragma unroll
        for (int p = 0; p < 2; ++p) {          // ni-pair halves
            __syncthreads();
            bf16_t* chunk = (bf16_t*)smem + wid * 4224;  // 32 n x [b:4][t:32], stride 132
            #pragma unroll
            for (int mi = 0; mi < 8; ++mi) {
                #pragma unroll
                for (int nio = 0; nio < 2; ++nio) {
                    const int ni = p * 2 + nio;
                    const int nl = nio * 16 + frow;
                    #pragma unroll
                    for (int j = 0; j < 4; ++j) {   // j == b
                        float v = acc[mi][ni][j] + bb[ni];
                        v = v / (1.f + __expf(-v));
                        chunk[nl * 132 + j * 32 + mi * 4 + c] = (bf16_t)v;
                    }
                }
            }
            __syncthreads();
            const int nl  = lane & 31;
            const int bh2 = lane >> 5;
            const int hd  = wrn + p * 32 + nl;
            const int t0  = (m0 + wrm) >> 2;
            #pragma unroll
            for (int bi = 0; bi < 2; ++bi) {
                const int b2 = bh2 * 2 + bi;
                const bf16_t* src = chunk + nl * 132 + b2 * 32;
                bf16_t* dst = Cb + (((size_t)hh * 4 + b2) * 256 + hd) * (size_t)LQ + t0;
                #pragma unroll
                for (int q = 0; q < 4; ++q)
                    *(bf16x8*)(dst + q * 8) = *(const bf16x8*)(src + q * 8);
            }
        }
        return;
    }

    // epilogue (MODE 0 / 2): C/D layout col(n)=frow, row(m)=c*4+j
    const int fq = c * 4;
    #pragma unroll
    for (int mi = 0; mi < MI; ++mi) {
        #pragma unroll
        for (int ni = 0; ni < 4; ++ni) {
            const int gn = n0 + wrn + ni * 16 + frow;
            #pragma unroll
            for (int j = 0; j < 4; ++j) {
                const int gm = m0 + wrm + mi * 16 + fq + j;
                float v = acc[mi][ni][j];
                if constexpr (MODE == 0) {
                    v += bias[gn];
                    v = v / (1.f + __expf(-v));
                    Cb[(size_t)gm * N + gn] = (bf16_t)v;
                } else {
                    v += bias[gn] + res[(size_t)gm * N + gn];
                    Cf[(size_t)gm * N + gn] = v;
                }
            }
        }
    }
}

// ---------------------------------------------------------------- Toeplitz GEMM
// Per head h: out[t,n] = sum_s T_h[t,s] * VT[h][n][s], n = b*256+hd (N=1024).
// BM=128, BN=256, BK=32; 8 waves (2M x 4N), wave tile 64x64, acc[4][4].
// Same counted-vmcnt triple-buffer pipeline + swizzle as gemm_p; 72 KB LDS,
// 2 blocks/CU; heavy-first 1-D grid of 512 blocks; causal NT = 4*m_blk+4.
__global__ __launch_bounds__(512, 2) void gemm_toep_p(
    const bf16_t* __restrict__ VT, const bf16_t* __restrict__ Atiles,
    const bf16_t* __restrict__ U, bf16_t* __restrict__ O)
{
    constexpr int ABYTES = 8192;             // 128 rows x 64 B
    constexpr int BSTRIDE = ABYTES + 16384;  // + 256 rows x 64 B
    __shared__ alignas(16) char smem[3 * BSTRIDE];   // 72 KB

    const int bid   = blockIdx.x;          // 0..511
    const int m_blk = 15 - (bid >> 5);     // heavy-first
    const int sub   = bid & 31;
    const int h     = sub >> 2;
    const int n0    = (sub & 3) * 256;
    const int m0    = m_blk * 128;

    const int tid  = threadIdx.x;
    const int wid  = tid >> 6;
    const int lane = tid & 63;
    const int frow = lane & 15;
    const int c    = lane >> 4;
    const int wrm  = (wid >> 2) * 64;
    const int wrn  = (wid & 3) * 64;

    const int g = (frow >> 1) & 3;
    const int offA0 = (wrm + frow) * 64 + ((c ^ g) << 4);
    const int offB0 = ABYTES + (wrn + frow) * 64 + ((c ^ g) << 4);

    const int rA   = tid >> 2;
    const int soff = (((tid & 3) ^ ((rA >> 1) & 3)) << 4);
    const char* Ah = (const char*)Atiles + (size_t)h * 64 * 8192;
    const size_t ldb = (size_t)LQ * 2;
    const char* sB = (const char*)VT + ((size_t)h * 1024 + n0 + rA) * ldb + soff;

    auto STAGE = [&](int bf, int kt) {
        const int q = 4 * m_blk + 3 - kt;
        __builtin_amdgcn_global_load_lds(
            GAS1(Ah + (size_t)q * 8192 + (size_t)rA * 64 + soff),
            LAS3(smem + bf * BSTRIDE + wid * 1024), 16, 0, 0);
        char* dB = smem + bf * BSTRIDE + ABYTES + wid * 1024;
        __builtin_amdgcn_global_load_lds(GAS1(sB + (size_t)kt * 64), LAS3(dB), 16, 0, 0);
        __builtin_amdgcn_global_load_lds(GAS1(sB + 128 * ldb + (size_t)kt * 64),
                                         LAS3(dB + 8192), 16, 0, 0);
    };

    f32x4 acc[4][4];
    #pragma unroll
    for (int i = 0; i < 4; ++i)
        #pragma unroll
        for (int j = 0; j < 4; ++j) acc[i][j] = (f32x4){0.f, 0.f, 0.f, 0.f};

    const int NT = 4 * m_blk + 4;          // causal K-tiles

    STAGE(0, 0); STAGE(1, 1);
    asm volatile("s_waitcnt vmcnt(3)" ::: "memory");
    __builtin_amdgcn_s_barrier();

    int cur = 0, pb = 2;
    for (int t = 0; t < NT; ++t) {
        const char* base = smem + cur * BSTRIDE;
        bf16x8 av[4], bv[4];
        #pragma unroll
        for (int i = 0; i < 4; ++i)
            av[i] = *(const bf16x8*)(base + offA0 + i * 1024);
        #pragma unroll
        for (int i = 0; i < 4; ++i)
            bv[i] = *(const bf16x8*)(base + offB0 + i * 1024);
        if (t + 2 < NT) STAGE(pb, t + 2);
        __builtin_amdgcn_s_setprio(1);
        #pragma unroll
        for (int mi = 0; mi < 4; ++mi)
            #pragma unroll
            for (int ni = 0; ni < 4; ++ni)
                acc[mi][ni] = __builtin_amdgcn_mfma_f32_16x16x32_bf16(
                    av[mi], bv[ni], acc[mi][ni], 0, 0, 0);
        __builtin_amdgcn_s_setprio(0);
        if (t + 1 < NT) {
            if (t + 2 < NT) asm volatile("s_waitcnt vmcnt(3)" ::: "memory");
            else            asm volatile("s_waitcnt vmcnt(0)" ::: "memory");
            __builtin_amdgcn_s_barrier();
        }
        cur = (cur == 2) ? 0 : cur + 1;
        pb  = (pb  == 2) ? 0 : pb  + 1;
    }

    // epilogue: gate with U and scatter to (t*4+b, h*256+hd)
    const int fq = c * 4;
    #pragma unroll
    for (int mi = 0; mi < 4; ++mi) {
        #pragma unroll
        for (int ni = 0; ni < 4; ++ni) {
            const int nn = n0 + wrn + ni * 16 + frow;   // 0..1023
            const int b  = nn >> 8, hd = nn & 255;
            #pragma unroll
            for (int j = 0; j < 4; ++j) {
                const int t = m0 + wrm + mi * 16 + fq + j;
                const size_t idx = ((size_t)t * BQ + b) * D1Q + h * HDQ + hd;
                const float uval = (float)U[idx];
                O[idx] = (bf16_t)(uval * acc[mi][ni][j]);
            }
        }
    }
}

// ---------------------------------------------------------------- launch

extern "C" void kernel_launch(void* const* d_in, const int* in_sizes, int n_in,
                              void* d_out, int out_size, void* d_ws, size_t ws_size,
                              hipStream_t stream)
{
    const float* x    = (const float*)d_in[0];
    const float* Wu   = (const float*)d_in[1];
    const float* bu   = (const float*)d_in[2];
    const float* Wv   = (const float*)d_in[3];
    const float* bv   = (const float*)d_in[4];
    const float* Wo   = (const float*)d_in[5];
    const float* bo   = (const float*)d_in[6];
    const float* zero = (const float*)d_in[7];
    const float* pos  = (const float*)d_in[8];
    float* out = (float*)d_out;

    char* ws = (char*)d_ws;
    size_t off = 0;
    auto alloc = [&](size_t bytes) {
        char* p = ws + off;
        off += (bytes + 255) & ~(size_t)255;
        return p;
    };
    bf16_t* xn     = (bf16_t*)alloc((size_t)NBQ * EQ * 2);
    bf16_t* Wub    = (bf16_t*)alloc((size_t)D1Q * EQ * 2);
    bf16_t* Wvb    = (bf16_t*)alloc((size_t)D1Q * EQ * 2);
    bf16_t* Wob    = (bf16_t*)alloc((size_t)EQ * D1Q * 2);
    bf16_t* Atiles = (bf16_t*)alloc((size_t)HQ * 64 * 4096 * 2);
    bf16_t* Ub     = (bf16_t*)alloc((size_t)NBQ * D1Q * 2);
    bf16_t* VTb    = (bf16_t*)alloc((size_t)NBQ * D1Q * 2);   // (h,b,hd,t)
    bf16_t* Ob     = (bf16_t*)alloc((size_t)NBQ * D1Q * 2);

    convert_kernel<<<8192, 256, 0, stream>>>(Wu, Wv, Wo, Wub, Wvb, Wob);
    build_toep_tiles<<<dim3(64, 8), 256, 0, stream>>>(zero, pos, Atiles);
    rmsnorm_kernel<<<NBQ, 256, 0, stream>>>(x, xn);

    // U: BM=256 BN=128, 512 blocks, 2 blocks/CU
    dim3 gU(D1Q / 128, NBQ / 256);   // (16, 32)
    gemm_p<4, 4, 2, 0, 2><<<gU, 512, 0, stream>>>(xn, Wub, EQ, D1Q, bu, nullptr, Ub, nullptr);
    // V: BM=256 BN=256 (transpose epilogue), 256 blocks
    dim3 gV(D1Q / 256, NBQ / 256);   // (8, 32)
    gemm_p<8, 2, 4, 1, 1><<<gV, 512, 0, stream>>>(xn, Wvb, EQ, D1Q, bv, nullptr, VTb, nullptr);

    gemm_toep_p<<<512, 512, 0, stream>>>(VTb, Atiles, Ub, Ob);

    // final: M=8192, N=1024, K=2048 — BM=256 BN=128, 256 blocks
    dim3 g2(EQ / 128, NBQ / 256);    // (8, 32)
    gemm_p<4, 4, 2, 2, 2><<<g2, 512, 0, stream>>>(Ob, Wob, D1Q, EQ, bo, x, nullptr, out);
}

// Round 8
// 198.204 us; speedup vs baseline: 1.3801x; 1.0435x over previous
//
#include <hip/hip_runtime.h>
#include <cstdint>
#include <cstddef>

#define LQ   2048
#define BQ   4
#define EQ   1024
#define HQ   8
#define D1Q  2048
#define HDQ  256
#define NBQ  (LQ*BQ)   // 8192 rows in (n,b) layout

typedef __bf16 bf16_t;
typedef __bf16 bf16x8 __attribute__((ext_vector_type(8)));
typedef __bf16 bf16x4 __attribute__((ext_vector_type(4)));
typedef float  f32x4  __attribute__((ext_vector_type(4)));

#define GAS1(p) ((const __attribute__((address_space(1))) void*)(p))
#define LAS3(p) ((__attribute__((address_space(3))) void*)(p))

// ---------------------------------------------------------------- utilities

__global__ __launch_bounds__(256) void convert_kernel(
    const float* __restrict__ Wu, const float* __restrict__ Wv,
    const float* __restrict__ Wo,
    bf16_t* __restrict__ Wub, bf16_t* __restrict__ Wvb,
    bf16_t* __restrict__ Wob)
{
    const size_t i = (size_t)blockIdx.x * 256 + threadIdx.x;
    if (i < (size_t)D1Q * EQ) {
        Wub[i] = (bf16_t)Wu[i];
        Wvb[i] = (bf16_t)Wv[i];
        Wob[i] = (bf16_t)Wo[i];
    }
}

// Precompute Toeplitz A-tiles, 128 rows x 64 cols (BK=64), diag offset (q-1)*64.
// T[r][c] = coef[doff + r - c]  (0 if d<0).  32 tiles x 8 heads x 16KB = 4MB.
__global__ __launch_bounds__(256) void build_toep_tiles2(
    const float* __restrict__ zero, const float* __restrict__ pos,
    bf16_t* __restrict__ At)
{
    const int q = blockIdx.x;        // 0..31
    const int h = blockIdx.y;        // 0..7
    const int doff = (q - 1) * 64;
    const int tid = threadIdx.x;
    bf16_t* dst = At + ((size_t)h * 32 + q) * 8192;
    const int r  = tid >> 1;
    const int c0 = (tid & 1) * 32;
    bf16_t vals[32];
    #pragma unroll
    for (int j = 0; j < 32; ++j) {
        const int d = doff + r - (c0 + j);
        float v = 0.f;
        if (d == 0) v = zero[h];
        else if (d > 0 && d < LQ) v = pos[(size_t)h * (LQ - 1) + d - 1];
        vals[j] = (bf16_t)v;
    }
    #pragma unroll
    for (int qq = 0; qq < 4; ++qq)
        *(bf16x8*)(dst + r * 64 + c0 + qq * 8) = *(bf16x8*)(vals + qq * 8);
}

__global__ __launch_bounds__(256) void rmsnorm_kernel(
    const float* __restrict__ x, bf16_t* __restrict__ xn)
{
    const int row = blockIdx.x;           // 0..8191
    const int tid = threadIdx.x;
    const float4 v = ((const float4*)(x + (size_t)row * EQ))[tid];
    float ss = v.x*v.x + v.y*v.y + v.z*v.z + v.w*v.w;
    #pragma unroll
    for (int m = 32; m >= 1; m >>= 1) ss += __shfl_xor(ss, m, 64);
    __shared__ float red[4];
    const int wid = tid >> 6, lane = tid & 63;
    if (lane == 0) red[wid] = ss;
    __syncthreads();
    const float tot = red[0] + red[1] + red[2] + red[3];
    const float inv = 1.f / (sqrtf(tot * (1.f / EQ)) + 1e-8f);
    bf16x4 o;
    o[0] = (bf16_t)(v.x * inv); o[1] = (bf16_t)(v.y * inv);
    o[2] = (bf16_t)(v.z * inv); o[3] = (bf16_t)(v.w * inv);
    *(bf16x4*)(xn + (size_t)row * EQ + tid * 4) = o;
}

// ---------------------------------------------------------------- phase primitive
// One pipeline phase: {ds_read 4 av (+4 bv) ; issue stage ; barrier ; 16 MFMA ;
// optional counted vmcnt ; barrier}.  All acc indices compile-time (KK/MH templ).
// LDS rows are 128 B (BK=64), 8x16B slots, XOR-swizzled by row&7 (both sides).

template<int KK, int MH, int WAITN, bool LDB, int MI_, typename F>
__device__ __forceinline__ void phase_op(const char* base, int offA0, int offB0,
    bf16x8 (&bv)[4], f32x4 (&acc)[MI_][4], F&& stage)
{
    bf16x8 av[4];
    #pragma unroll
    for (int i = 0; i < 4; ++i)
        av[i] = *(const bf16x8*)(base + (offA0 ^ (KK << 6)) + (MH * 4 + i) * 2048);
    if constexpr (LDB) {
        #pragma unroll
        for (int i = 0; i < 4; ++i)
            bv[i] = *(const bf16x8*)(base + (offB0 ^ (KK << 6)) + i * 2048);
    }
    stage();
    __builtin_amdgcn_s_barrier();
    __builtin_amdgcn_s_setprio(1);
    #pragma unroll
    for (int i = 0; i < 4; ++i)
        #pragma unroll
        for (int ni = 0; ni < 4; ++ni)
            acc[MH * 4 + i][ni] = __builtin_amdgcn_mfma_f32_16x16x32_bf16(
                av[i], bv[ni], acc[MH * 4 + i][ni], 0, 0, 0);
    __builtin_amdgcn_s_setprio(0);
    if constexpr (WAITN >= 0)
        asm volatile("s_waitcnt vmcnt(%0)" :: "i"(WAITN) : "memory");
    __builtin_amdgcn_s_barrier();
}

// ---------------------------------------------------------------- 8-phase 256x256 GEMM
// C[m,n] = sum_k A[m,k]*B[n,k].  BM=BN=256, BK=64, 8 waves (2M x 4N), wave tile
// 128x64, acc[8][4].  2 LDS buffers (128 KB).  8 phases / 2 K-tiles; stage one
// 16KB half-tile (2 gload_lds) per phase; vmcnt(2) only at phases 4 and 8.
// MODE 0: silu->bf16 row-major   1: silu->bf16 (h,b,hd,t) LDS-transposed

template<int MODE>
__global__ __launch_bounds__(512, 1) void gemm_big(
    const bf16_t* __restrict__ A, const bf16_t* __restrict__ Bm,
    int K, int N, const float* __restrict__ bias, bf16_t* __restrict__ Cb)
{
    constexpr int BSTRIDE = 65536;            // A 32K + B 32K
    __shared__ alignas(16) char smem[2 * BSTRIDE];

    // XCD-chunked bijective swizzle (nwg % 8 == 0)
    const int nwg   = gridDim.x * gridDim.y;
    const int bid0  = blockIdx.y * gridDim.x + blockIdx.x;
    const int chunkw = nwg >> 3;
    const int sb    = (bid0 & 7) * chunkw + (bid0 >> 3);
    const int bx    = sb % gridDim.x;
    const int by    = sb / gridDim.x;

    const int tid  = threadIdx.x;
    const int wid  = tid >> 6;
    const int lane = tid & 63;
    const int frow = lane & 15;
    const int c    = lane >> 4;
    const int m0 = by * 256;
    const int n0 = bx * 256;
    const int wrm = (wid >> 2) * 128;
    const int wrn = (wid & 3) * 64;

    const int g = frow & 7;
    const int offA0 = (wrm + frow) * 128 + ((c ^ g) << 4);
    const int offB0 = 32768 + (wrn + frow) * 128 + ((c ^ g) << 4);

    const int rl = tid >> 3;                  // 0..63
    const int ls = (tid & 7) ^ (rl & 7);
    const size_t lda2 = (size_t)K * 2;
    const char* sA = (const char*)A  + (size_t)(m0 + rl) * lda2 + ls * 16;
    const char* sB = (const char*)Bm + (size_t)(n0 + rl) * lda2 + ls * 16;

    // stage half-tile hf of operand op (0=A,1=B) of K-tile kt into buffer bf
    auto SH = [&](int bf, int op, int hf, int kt) {
        const char* s = (op ? sB : sA) + (size_t)(hf * 128) * lda2 + (size_t)kt * 128;
        char* d = smem + bf * BSTRIDE + op * 32768 + hf * 16384 + wid * 1024;
        __builtin_amdgcn_global_load_lds(GAS1(s), LAS3(d), 16, 0, 0);
        __builtin_amdgcn_global_load_lds(GAS1(s + 64 * lda2), LAS3(d + 8192), 16, 0, 0);
    };

    f32x4 acc[8][4];
    #pragma unroll
    for (int i = 0; i < 8; ++i)
        #pragma unroll
        for (int j = 0; j < 4; ++j) acc[i][j] = (f32x4){0.f, 0.f, 0.f, 0.f};
    bf16x8 bv[4];

    const int NT = K >> 6;                    // 16 (even)

    // prologue: tile0 fully into buf0, B0(tile1) into buf1
    SH(0,0,0,0); SH(0,0,1,0); SH(0,1,0,0); SH(0,1,1,0); SH(1,1,0,1);
    asm volatile("s_waitcnt vmcnt(2)" ::: "memory");
    __builtin_amdgcn_s_barrier();

    const char* b0 = smem;
    const char* b1 = smem + BSTRIDE;
    for (int i = 0; i < NT / 2; ++i) {
        const int t1 = 2 * i + 1, t2 = 2 * i + 2;
        const bool p2 = t2 < NT, p3 = t2 + 1 < NT;
        phase_op<0,0,-1,true >(b0, offA0, offB0, bv, acc, [&]{ SH(1,1,1,t1); });
        phase_op<0,1,-1,false>(b0, offA0, offB0, bv, acc, [&]{ SH(1,0,0,t1); });
        phase_op<1,0,-1,true >(b0, offA0, offB0, bv, acc, [&]{ SH(1,0,1,t1); });
        phase_op<1,1, 2,false>(b0, offA0, offB0, bv, acc, [&]{ if (p2) SH(0,1,0,t2); });
        phase_op<0,0,-1,true >(b1, offA0, offB0, bv, acc, [&]{ if (p2) SH(0,1,1,t2); });
        phase_op<0,1,-1,false>(b1, offA0, offB0, bv, acc, [&]{ if (p2) SH(0,0,0,t2); });
        phase_op<1,0,-1,true >(b1, offA0, offB0, bv, acc, [&]{ if (p2) SH(0,0,1,t2); });
        phase_op<1,1, 2,false>(b1, offA0, offB0, bv, acc, [&]{ if (p3) SH(1,1,0,t2+1); });
    }

    if constexpr (MODE == 1) {
        // LDS-staged transpose epilogue -> (h, b, hd, t), full 64-B t-runs.
        const int hh = n0 >> 8;
        float bb[4];
        #pragma unroll
        for (int ni = 0; ni < 4; ++ni) bb[ni] = bias[n0 + wrn + ni * 16 + frow];

        #pragma unroll
        for (int p = 0; p < 2; ++p) {          // ni-pair halves
            __syncthreads();
            bf16_t* chunk = (bf16_t*)smem + wid * 4224;  // 32 n x [b:4][t:32], stride 132
            #pragma unroll
            for (int mi = 0; mi < 8; ++mi) {
                #pragma unroll
                for (int nio = 0; nio < 2; ++nio) {
                    const int ni = p * 2 + nio;
                    const int nl = nio * 16 + frow;
                    #pragma unroll
                    for (int j = 0; j < 4; ++j) {   // j == b
                        float v = acc[mi][ni][j] + bb[ni];
                        v = v / (1.f + __expf(-v));
                        chunk[nl * 132 + j * 32 + mi * 4 + c] = (bf16_t)v;
                    }
                }
            }
            __syncthreads();
            const int nl  = lane & 31;
            const int bh2 = lane >> 5;
            const int hd  = wrn + p * 32 + nl;
            const int t0  = (m0 + wrm) >> 2;
            #pragma unroll
            for (int bi = 0; bi < 2; ++bi) {
                const int b2 = bh2 * 2 + bi;
                const bf16_t* src = chunk + nl * 132 + b2 * 32;
                bf16_t* dst = Cb + (((size_t)hh * 4 + b2) * 256 + hd) * (size_t)LQ + t0;
                #pragma unroll
                for (int q = 0; q < 4; ++q)
                    *(bf16x8*)(dst + q * 8) = *(const bf16x8*)(src + q * 8);
            }
        }
        return;
    }

    // MODE 0 epilogue: silu(acc+bias) -> bf16 row-major
    const int fq = c * 4;
    #pragma unroll
    for (int mi = 0; mi < 8; ++mi) {
        #pragma unroll
        for (int ni = 0; ni < 4; ++ni) {
            const int gn = n0 + wrn + ni * 16 + frow;
            #pragma unroll
            for (int j = 0; j < 4; ++j) {
                const int gm = m0 + wrm + mi * 16 + fq + j;
                float v = acc[mi][ni][j] + bias[gn];
                v = v / (1.f + __expf(-v));
                Cb[(size_t)gm * N + gn] = (bf16_t)v;
            }
        }
    }
}

// ---------------------------------------------------------------- 4-phase 128x256 GEMM (final)
// BM=128, BN=256, BK=64; 8 waves (2M x 4N), wave tile 64x64, acc[4][4].
// 3 LDS buffers x 48KB (144 KB); tile t+2 staged during tile t; boundary vmcnt(6).
// Epilogue: acc + bias + residual -> f32 row-major.
__global__ __launch_bounds__(512, 1) void gemm_fin(
    const bf16_t* __restrict__ A, const bf16_t* __restrict__ Bm,
    const float* __restrict__ bias, const float* __restrict__ res,
    float* __restrict__ Cf)
{
    constexpr int K = D1Q, N = EQ;
    constexpr int BSTRIDE = 49152;            // A 16K + B 32K
    __shared__ alignas(16) char smem[3 * BSTRIDE];

    const int nwg   = gridDim.x * gridDim.y;
    const int bid0  = blockIdx.y * gridDim.x + blockIdx.x;
    const int chunkw = nwg >> 3;
    const int sb    = (bid0 & 7) * chunkw + (bid0 >> 3);
    const int bx    = sb % gridDim.x;
    const int by    = sb / gridDim.x;

    const int tid  = threadIdx.x;
    const int wid  = tid >> 6;
    const int lane = tid & 63;
    const int frow = lane & 15;
    const int c    = lane >> 4;
    const int m0 = by * 128;
    const int n0 = bx * 256;
    const int wrm = (wid >> 2) * 64;
    const int wrn = (wid & 3) * 64;

    const int g = frow & 7;
    const int offA0 = (wrm + frow) * 128 + ((c ^ g) << 4);
    const int offB0 = 16384 + (wrn + frow) * 128 + ((c ^ g) << 4);

    const int rl = tid >> 3;
    const int ls = (tid & 7) ^ (rl & 7);
    const size_t lda2 = (size_t)K * 2;
    const char* sA = (const char*)A  + (size_t)(m0 + rl) * lda2 + ls * 16;
    const char* sB = (const char*)Bm + (size_t)(n0 + rl) * lda2 + ls * 16;

    auto SH_A = [&](int bf, int kt) {
        const char* s = sA + (size_t)kt * 128;
        char* d = smem + bf * BSTRIDE + wid * 1024;
        __builtin_amdgcn_global_load_lds(GAS1(s), LAS3(d), 16, 0, 0);
        __builtin_amdgcn_global_load_lds(GAS1(s + 64 * lda2), LAS3(d + 8192), 16, 0, 0);
    };
    auto SH_B = [&](int bf, int hf, int kt) {
        const char* s = sB + (size_t)(hf * 128) * lda2 + (size_t)kt * 128;
        char* d = smem + bf * BSTRIDE + 16384 + hf * 16384 + wid * 1024;
        __builtin_amdgcn_global_load_lds(GAS1(s), LAS3(d), 16, 0, 0);
        __builtin_amdgcn_global_load_lds(GAS1(s + 64 * lda2), LAS3(d + 8192), 16, 0, 0);
    };

    f32x4 acc[4][4];
    #pragma unroll
    for (int i = 0; i < 4; ++i)
        #pragma unroll
        for (int j = 0; j < 4; ++j) acc[i][j] = (f32x4){0.f, 0.f, 0.f, 0.f};
    bf16x8 bv[4];

    const int NT = K >> 6;                    // 32

    SH_A(0, 0); SH_B(0, 0, 0); SH_B(0, 1, 0);
    SH_A(1, 1); SH_B(1, 0, 1); SH_B(1, 1, 1);
    asm volatile("s_waitcnt vmcnt(6)" ::: "memory");
    __builtin_amdgcn_s_barrier();

    int cur = 0, pb = 2;
    for (int t = 0; t < NT; ++t) {
        const char* base = smem + cur * BSTRIDE;
        const int t2 = t + 2;
        const bool pf = t2 < NT;
        phase_op<0,0,-1,true>(base, offA0, offB0, bv, acc,
            [&]{ if (pf) { SH_A(pb, t2); SH_B(pb, 0, t2); } });
        phase_op<1,0, 6,true>(base, offA0, offB0, bv, acc,
            [&]{ if (pf) SH_B(pb, 1, t2); });
        cur = (cur == 2) ? 0 : cur + 1;
        pb  = (pb  == 2) ? 0 : pb  + 1;
    }

    const int fq = c * 4;
    #pragma unroll
    for (int mi = 0; mi < 4; ++mi) {
        #pragma unroll
        for (int ni = 0; ni < 4; ++ni) {
            const int gn = n0 + wrn + ni * 16 + frow;
            #pragma unroll
            for (int j = 0; j < 4; ++j) {
                const int gm = m0 + wrm + mi * 16 + fq + j;
                Cf[(size_t)gm * N + gn] =
                    acc[mi][ni][j] + bias[gn] + res[(size_t)gm * N + gn];
            }
        }
    }
}

// ---------------------------------------------------------------- 4-phase Toeplitz GEMM
// Per head h: out[t,n] = sum_s T_h[t,s] * VT[h][n][s], n = b*256+hd (N=1024).
// BM=128, BN=256, BK=64; A from precomputed 128x64 tiles (q' = 2*m_blk - kt + 1);
// causal NT = 2*m_blk+2; heavy-first 512 blocks; same 3-buffer pipeline as gemm_fin.
__global__ __launch_bounds__(512, 1) void gemm_toep4p(
    const bf16_t* __restrict__ VT, const bf16_t* __restrict__ Atl,
    const bf16_t* __restrict__ U, bf16_t* __restrict__ O)
{
    constexpr int BSTRIDE = 49152;
    __shared__ alignas(16) char smem[3 * BSTRIDE];

    const int bid   = blockIdx.x;          // 0..511
    const int m_blk = 15 - (bid >> 5);     // heavy-first
    const int sub   = bid & 31;
    const int h     = sub >> 2;
    const int n0    = (sub & 3) * 256;
    const int m0    = m_blk * 128;

    const int tid  = threadIdx.x;
    const int wid  = tid >> 6;
    const int lane = tid & 63;
    const int frow = lane & 15;
    const int c    = lane >> 4;
    const int wrm  = (wid >> 2) * 64;
    const int wrn  = (wid & 3) * 64;

    const int g = frow & 7;
    const int offA0 = (wrm + frow) * 128 + ((c ^ g) << 4);
    const int offB0 = 16384 + (wrn + frow) * 128 + ((c ^ g) << 4);

    const int rl = tid >> 3;
    const int ls = (tid & 7) ^ (rl & 7);
    const char* Ah = (const char*)Atl + (size_t)h * 32 * 16384;
    const size_t ldb = (size_t)LQ * 2;
    const char* sB = (const char*)VT + ((size_t)h * 1024 + n0 + rl) * ldb + ls * 16;

    auto SH_A = [&](int bf, int kt) {
        const int q = 2 * m_blk - kt + 1;
        const char* s = Ah + (size_t)q * 16384 + (size_t)rl * 128 + ls * 16;
        char* d = smem + bf * BSTRIDE + wid * 1024;
        __builtin_amdgcn_global_load_lds(GAS1(s), LAS3(d), 16, 0, 0);
        __builtin_amdgcn_global_load_lds(GAS1(s + 64 * 128), LAS3(d + 8192), 16, 0, 0);
    };
    auto SH_B = [&](int bf, int hf, int kt) {
        const char* s = sB + (size_t)(hf * 128) * ldb + (size_t)kt * 128;
        char* d = smem + bf * BSTRIDE + 16384 + hf * 16384 + wid * 1024;
        __builtin_amdgcn_global_load_lds(GAS1(s), LAS3(d), 16, 0, 0);
        __builtin_amdgcn_global_load_lds(GAS1(s + 64 * ldb), LAS3(d + 8192), 16, 0, 0);
    };

    f32x4 acc[4][4];
    #pragma unroll
    for (int i = 0; i < 4; ++i)
        #pragma unroll
        for (int j = 0; j < 4; ++j) acc[i][j] = (f32x4){0.f, 0.f, 0.f, 0.f};
    bf16x8 bv[4];

    const int NT = 2 * m_blk + 2;          // causal BK=64 tiles (even)

    SH_A(0, 0); SH_B(0, 0, 0); SH_B(0, 1, 0);
    SH_A(1, 1); SH_B(1, 0, 1); SH_B(1, 1, 1);
    asm volatile("s_waitcnt vmcnt(6)" ::: "memory");
    __builtin_amdgcn_s_barrier();

    int cur = 0, pb = 2;
    for (int t = 0; t < NT; ++t) {
        const char* base = smem + cur * BSTRIDE;
        const int t2 = t + 2;
        const bool pf = t2 < NT;
        phase_op<0,0,-1,true>(base, offA0, offB0, bv, acc,
            [&]{ if (pf) { SH_A(pb, t2); SH_B(pb, 0, t2); } });
        phase_op<1,0, 6,true>(base, offA0, offB0, bv, acc,
            [&]{ if (pf) SH_B(pb, 1, t2); });
        cur = (cur == 2) ? 0 : cur + 1;
        pb  = (pb  == 2) ? 0 : pb  + 1;
    }

    // epilogue: gate with U and scatter to (t*4+b, h*256+hd)
    const int fq = c * 4;
    #pragma unroll
    for (int mi = 0; mi < 4; ++mi) {
        #pragma unroll
        for (int ni = 0; ni < 4; ++ni) {
            const int nn = n0 + wrn + ni * 16 + frow;   // 0..1023
            const int b  = nn >> 8, hd = nn & 255;
            #pragma unroll
            for (int j = 0; j < 4; ++j) {
                const int t = m0 + wrm + mi * 16 + fq + j;
                const size_t idx = ((size_t)t * BQ + b) * D1Q + h * HDQ + hd;
                const float uval = (float)U[idx];
                O[idx] = (bf16_t)(uval * acc[mi][ni][j]);
            }
        }
    }
}

// ---------------------------------------------------------------- launch

extern "C" void kernel_launch(void* const* d_in, const int* in_sizes, int n_in,
                              void* d_out, int out_size, void* d_ws, size_t ws_size,
                              hipStream_t stream)
{
    const float* x    = (const float*)d_in[0];
    const float* Wu   = (const float*)d_in[1];
    const float* bu   = (const float*)d_in[2];
    const float* Wv   = (const float*)d_in[3];
    const float* bv   = (const float*)d_in[4];
    const float* Wo   = (const float*)d_in[5];
    const float* bo   = (const float*)d_in[6];
    const float* zero = (const float*)d_in[7];
    const float* pos  = (const float*)d_in[8];
    float* out = (float*)d_out;

    char* ws = (char*)d_ws;
    size_t off = 0;
    auto alloc = [&](size_t bytes) {
        char* p = ws + off;
        off += (bytes + 255) & ~(size_t)255;
        return p;
    };
    bf16_t* xn     = (bf16_t*)alloc((size_t)NBQ * EQ * 2);
    bf16_t* Wub    = (bf16_t*)alloc((size_t)D1Q * EQ * 2);
    bf16_t* Wvb    = (bf16_t*)alloc((size_t)D1Q * EQ * 2);
    bf16_t* Wob    = (bf16_t*)alloc((size_t)EQ * D1Q * 2);
    bf16_t* Atiles = (bf16_t*)alloc((size_t)HQ * 32 * 8192 * 2);  // 4 MB
    bf16_t* Ub     = (bf16_t*)alloc((size_t)NBQ * D1Q * 2);
    bf16_t* VTb    = (bf16_t*)alloc((size_t)NBQ * D1Q * 2);   // (h,b,hd,t)
    bf16_t* Ob     = (bf16_t*)alloc((size_t)NBQ * D1Q * 2);

    convert_kernel<<<8192, 256, 0, stream>>>(Wu, Wv, Wo, Wub, Wvb, Wob);
    build_toep_tiles2<<<dim3(32, 8), 256, 0, stream>>>(zero, pos, Atiles);
    rmsnorm_kernel<<<NBQ, 256, 0, stream>>>(x, xn);

    // U and V: M=8192, N=2048, K=1024 — 256x256 tiles, 256 blocks, 8-phase
    dim3 g1(D1Q / 256, NBQ / 256);   // (8, 32)
    gemm_big<0><<<g1, 512, 0, stream>>>(xn, Wub, EQ, D1Q, bu, Ub);
    gemm_big<1><<<g1, 512, 0, stream>>>(xn, Wvb, EQ, D1Q, bv, VTb);

    gemm_toep4p<<<512, 512, 0, stream>>>(VTb, Atiles, Ub, Ob);

    // final: M=8192, N=1024, K=2048 — 128x256 tiles, 256 blocks, 4-phase
    dim3 g2(EQ / 256, NBQ / 128);    // (4, 64)
    gemm_fin<<<g2, 512, 0, stream>>>(Ob, Wob, bo, x, out);
}